// Round 1
// baseline (890.824 us; speedup 1.0000x reference)
//
#include <hip/hip_runtime.h>
#include <cstdint>
#include <cstddef>

#define N_NODES 100000
#define N_EDGES 1600000
#define F_IN 256
#define F_HID 128
#define F_OUT 40

#define SCAN_CHUNK 1024
#define N_CHUNKS ((N_NODES + SCAN_CHUNK - 1) / SCAN_CHUNK)  // 98

// ---------------- degree count ----------------
__global__ void k_count(const int* __restrict__ dst, int* __restrict__ cnt) {
    int e = blockIdx.x * blockDim.x + threadIdx.x;
    if (e < N_EDGES) atomicAdd(&cnt[dst[e]], 1);
}

__global__ void k_dinv(const int* __restrict__ cnt, float* __restrict__ dinv) {
    int n = blockIdx.x * blockDim.x + threadIdx.x;
    if (n < N_NODES) dinv[n] = rsqrtf((float)cnt[n] + 1.0f);  // +1 self-loop
}

// ---------------- exclusive scan of cnt -> off (3 phases) ----------------
__global__ void k_scan_partial(const int* __restrict__ cnt, int* __restrict__ bsum) {
    __shared__ int sdata[256];
    int b = blockIdx.x, t = threadIdx.x;
    int base = b * SCAN_CHUNK;
    int sum = 0;
    for (int i = t; i < SCAN_CHUNK; i += 256) {
        int idx = base + i;
        sum += (idx < N_NODES) ? cnt[idx] : 0;
    }
    sdata[t] = sum;
    __syncthreads();
    for (int s = 128; s > 0; s >>= 1) {
        if (t < s) sdata[t] += sdata[t + s];
        __syncthreads();
    }
    if (t == 0) bsum[b] = sdata[0];
}

__global__ void k_scan_bsum(int* __restrict__ bsum) {
    if (threadIdx.x == 0 && blockIdx.x == 0) {
        int run = 0;
        for (int i = 0; i < N_CHUNKS; ++i) { int v = bsum[i]; bsum[i] = run; run += v; }
    }
}

__global__ void k_scan_final(const int* __restrict__ cnt, const int* __restrict__ bsum,
                             int* __restrict__ off, int* __restrict__ cur) {
    __shared__ int tsum[256];
    int b = blockIdx.x, t = threadIdx.x;
    int base = b * SCAN_CHUNK;
    int v[4]; int local = 0;
    #pragma unroll
    for (int i = 0; i < 4; ++i) {
        int idx = base + t * 4 + i;
        v[i] = (idx < N_NODES) ? cnt[idx] : 0;
        local += v[i];
    }
    tsum[t] = local;
    __syncthreads();
    for (int ofs = 1; ofs < 256; ofs <<= 1) {
        int y = (t >= ofs) ? tsum[t - ofs] : 0;
        __syncthreads();
        tsum[t] += y;
        __syncthreads();
    }
    int run = bsum[b] + tsum[t] - local;  // exclusive prefix for this thread
    #pragma unroll
    for (int i = 0; i < 4; ++i) {
        int idx = base + t * 4 + i;
        if (idx < N_NODES) { off[idx] = run; cur[idx] = run; }
        run += v[i];
    }
    if (b == 0 && t == 0) off[N_NODES] = N_EDGES;
}

// ---------------- scatter edges into CSR order ----------------
__global__ void k_scatter(const int* __restrict__ src, const int* __restrict__ dst,
                          int* __restrict__ cur, int* __restrict__ ssrc) {
    int e = blockIdx.x * blockDim.x + threadIdx.x;
    if (e < N_EDGES) {
        int d = dst[e];
        int p = atomicAdd(&cur[d], 1);
        ssrc[p] = src[e];
    }
}

// ---------------- GEMM1: x[N,256] @ W1[256,128] -> h[N,128] (f32) ----------------
#define G1_BM 64
#define G1_BN 128
#define G1_BK 32
__global__ __launch_bounds__(256) void k_gemm1(const float* __restrict__ A,
                                               const float* __restrict__ B,
                                               float* __restrict__ C) {
    __shared__ float As[G1_BM][G1_BK + 4];  // 36 floats/row, 16B-aligned rows
    __shared__ float Bs[G1_BK][G1_BN];
    int t = threadIdx.x;
    int tx = t & 31;   // cols tx*4 .. +3 (128)
    int ty = t >> 5;   // rows ty*8 .. +7 (64)
    int row0 = blockIdx.x * G1_BM;
    float acc[8][4] = {};
    for (int k0 = 0; k0 < F_IN; k0 += G1_BK) {
        #pragma unroll
        for (int i = 0; i < 2; ++i) {
            int idx = t + i * 256;        // 0..511
            int r = idx >> 3, v = idx & 7;
            int gr = row0 + r; if (gr > N_NODES - 1) gr = N_NODES - 1;
            float4 va = *(const float4*)(A + (size_t)gr * F_IN + k0 + v * 4);
            *(float4*)(&As[r][v * 4]) = va;
        }
        #pragma unroll
        for (int i = 0; i < 4; ++i) {
            int idx = t + i * 256;        // 0..1023
            int kk = idx >> 5, v = idx & 31;
            float4 vb = *(const float4*)(B + (size_t)(k0 + kk) * F_HID + v * 4);
            *(float4*)(&Bs[kk][v * 4]) = vb;
        }
        __syncthreads();
        #pragma unroll
        for (int kk = 0; kk < G1_BK; ++kk) {
            float4 b4 = *(const float4*)(&Bs[kk][tx * 4]);
            float b[4] = {b4.x, b4.y, b4.z, b4.w};
            float a[8];
            #pragma unroll
            for (int i = 0; i < 8; ++i) a[i] = As[ty * 8 + i][kk];
            #pragma unroll
            for (int i = 0; i < 8; ++i)
                #pragma unroll
                for (int j = 0; j < 4; ++j) acc[i][j] += a[i] * b[j];
        }
        __syncthreads();
    }
    #pragma unroll
    for (int i = 0; i < 8; ++i) {
        int gr = row0 + ty * 8 + i;
        if (gr < N_NODES) {
            float4 vo = make_float4(acc[i][0], acc[i][1], acc[i][2], acc[i][3]);
            *(float4*)(C + (size_t)gr * F_HID + tx * 4) = vo;
        }
    }
}

// ---------------- agg1: h1 = relu(D^-1/2 A D^-1/2 h + b1) ----------------
__global__ __launch_bounds__(256) void k_agg1(const float* __restrict__ h,
                                              const int* __restrict__ off,
                                              const int* __restrict__ ssrc,
                                              const float* __restrict__ dinv,
                                              const float* __restrict__ b1,
                                              float* __restrict__ h1) {
    int node = blockIdx.x * 2 + (threadIdx.x >> 7);
    int f = threadIdx.x & 127;
    if (node >= N_NODES) return;
    int s0 = off[node], s1 = off[node + 1];
    float dn = dinv[node];
    float acc = dn * h[(size_t)node * F_HID + f];  // self-loop term (x dn later)
    for (int e = s0; e < s1; ++e) {
        int s = ssrc[e];
        acc += dinv[s] * h[(size_t)s * F_HID + f];
    }
    float v = acc * dn + b1[f];
    h1[(size_t)node * F_HID + f] = fmaxf(v, 0.0f);
}

// ---------------- GEMM2: h1[N,128] @ W2[128,40] -> h2[N,40] (pad cols to 64) ----------------
#define G2_BM 64
#define G2_BN 64
#define G2_BK 32
__global__ __launch_bounds__(256) void k_gemm2(const float* __restrict__ A,
                                               const float* __restrict__ B,
                                               float* __restrict__ C) {
    __shared__ float As[G2_BM][G2_BK + 4];
    __shared__ float Bs[G2_BK][G2_BN];
    int t = threadIdx.x;
    int tx = t & 15;   // cols tx*4 .. +3 (64)
    int ty = t >> 4;   // rows ty*4 .. +3 (64)
    int row0 = blockIdx.x * G2_BM;
    float acc[4][4] = {};
    for (int k0 = 0; k0 < F_HID; k0 += G2_BK) {
        #pragma unroll
        for (int i = 0; i < 2; ++i) {
            int idx = t + i * 256;        // 0..511
            int r = idx >> 3, v = idx & 7;
            int gr = row0 + r; if (gr > N_NODES - 1) gr = N_NODES - 1;
            float4 va = *(const float4*)(A + (size_t)gr * F_HID + k0 + v * 4);
            *(float4*)(&As[r][v * 4]) = va;
        }
        #pragma unroll
        for (int i = 0; i < 2; ++i) {
            int idx = t + i * 256;        // 0..511
            int kk = idx >> 4, v = idx & 15;
            float4 vb = make_float4(0.f, 0.f, 0.f, 0.f);
            if (v * 4 < F_OUT)  // v<=9 -> cols 36..39 still in range
                vb = *(const float4*)(B + (size_t)(k0 + kk) * F_OUT + v * 4);
            *(float4*)(&Bs[kk][v * 4]) = vb;
        }
        __syncthreads();
        #pragma unroll
        for (int kk = 0; kk < G2_BK; ++kk) {
            float4 b4 = *(const float4*)(&Bs[kk][tx * 4]);
            float b[4] = {b4.x, b4.y, b4.z, b4.w};
            float a[4];
            #pragma unroll
            for (int i = 0; i < 4; ++i) a[i] = As[ty * 4 + i][kk];
            #pragma unroll
            for (int i = 0; i < 4; ++i)
                #pragma unroll
                for (int j = 0; j < 4; ++j) acc[i][j] += a[i] * b[j];
        }
        __syncthreads();
    }
    #pragma unroll
    for (int i = 0; i < 4; ++i) {
        int gr = row0 + ty * 4 + i;
        int c0 = tx * 4;
        if (gr < N_NODES && c0 < F_OUT) {
            float4 vo = make_float4(acc[i][0], acc[i][1], acc[i][2], acc[i][3]);
            *(float4*)(C + (size_t)gr * F_OUT + c0) = vo;
        }
    }
}

// ---------------- agg2 + bias + log_softmax (wave per node) ----------------
__global__ __launch_bounds__(256) void k_agg2(const float* __restrict__ h2,
                                              const int* __restrict__ off,
                                              const int* __restrict__ ssrc,
                                              const float* __restrict__ dinv,
                                              const float* __restrict__ b2,
                                              float* __restrict__ out) {
    int node = blockIdx.x * 4 + (threadIdx.x >> 6);
    int lane = threadIdx.x & 63;
    if (node >= N_NODES) return;
    int s0 = off[node], s1 = off[node + 1];
    float dn = dinv[node];
    float acc = 0.0f;
    if (lane < F_OUT) acc = dn * h2[(size_t)node * F_OUT + lane];
    for (int e = s0; e < s1; ++e) {
        int s = ssrc[e];
        if (lane < F_OUT) acc += dinv[s] * h2[(size_t)s * F_OUT + lane];
    }
    float v = (lane < F_OUT) ? (acc * dn + b2[lane]) : -3.4e38f;
    float m = v;
    #pragma unroll
    for (int o = 32; o > 0; o >>= 1) m = fmaxf(m, __shfl_xor(m, o));
    float ex = (lane < F_OUT) ? __expf(v - m) : 0.0f;
    float s = ex;
    #pragma unroll
    for (int o = 32; o > 0; o >>= 1) s += __shfl_xor(s, o);
    float ls = __logf(s);
    if (lane < F_OUT) out[(size_t)node * F_OUT + lane] = v - m - ls;
}

// ---------------- launch ----------------
static inline char* alignup(char* p) {
    return (char*)(((uintptr_t)p + 255) & ~(uintptr_t)255);
}

extern "C" void kernel_launch(void* const* d_in, const int* in_sizes, int n_in,
                              void* d_out, int out_size, void* d_ws, size_t ws_size,
                              hipStream_t stream) {
    const float* x  = (const float*)d_in[0];
    const int*   ei = (const int*)d_in[1];
    const float* W1 = (const float*)d_in[2];
    const float* b1 = (const float*)d_in[3];
    const float* W2 = (const float*)d_in[4];
    const float* b2 = (const float*)d_in[5];
    float* out = (float*)d_out;

    char* w = (char*)d_ws;
    int* cnt  = (int*)w;           w = alignup(w + (size_t)N_NODES * 4);
    int* off  = (int*)w;           w = alignup(w + (size_t)(N_NODES + 1) * 4);
    int* cur  = (int*)w;           w = alignup(w + (size_t)N_NODES * 4);
    int* ssrc = (int*)w;           w = alignup(w + (size_t)N_EDGES * 4);
    int* bsum = (int*)w;           w = alignup(w + (size_t)N_CHUNKS * 4);
    float* dinv = (float*)w;       w = alignup(w + (size_t)N_NODES * 4);
    float* h    = (float*)w;       w = alignup(w + (size_t)N_NODES * F_HID * 4);
    float* h1   = (float*)w;       w = alignup(w + (size_t)N_NODES * F_HID * 4);
    float* h2   = (float*)w;       w = alignup(w + (size_t)N_NODES * F_OUT * 4);

    const int* srcp = ei;
    const int* dstp = ei + N_EDGES;

    hipMemsetAsync(cnt, 0, (size_t)N_NODES * 4, stream);
    k_count<<<(N_EDGES + 255) / 256, 256, 0, stream>>>(dstp, cnt);
    k_dinv<<<(N_NODES + 255) / 256, 256, 0, stream>>>(cnt, dinv);
    k_scan_partial<<<N_CHUNKS, 256, 0, stream>>>(cnt, bsum);
    k_scan_bsum<<<1, 64, 0, stream>>>(bsum);
    k_scan_final<<<N_CHUNKS, 256, 0, stream>>>(cnt, bsum, off, cur);
    k_scatter<<<(N_EDGES + 255) / 256, 256, 0, stream>>>(srcp, dstp, cur, ssrc);

    k_gemm1<<<(N_NODES + G1_BM - 1) / G1_BM, 256, 0, stream>>>(x, W1, h);
    k_agg1<<<(N_NODES + 1) / 2, 256, 0, stream>>>(h, off, ssrc, dinv, b1, h1);
    k_gemm2<<<(N_NODES + G2_BM - 1) / G2_BM, 256, 0, stream>>>(h1, W2, h2);
    k_agg2<<<(N_NODES + 3) / 4, 256, 0, stream>>>(h2, off, ssrc, dinv, b2, out);
}

// Round 2
// 598.735 us; speedup vs baseline: 1.4878x; 1.4878x over previous
//
#include <hip/hip_runtime.h>
#include <cstdint>
#include <cstddef>

#define N_NODES 100000
#define N_EDGES 1600000
#define F_IN 256
#define F_HID 128
#define F_OUT 40

#define SCAN_CHUNK 1024
#define N_CHUNKS ((N_NODES + SCAN_CHUNK - 1) / SCAN_CHUNK)  // 98

// ---------------- degree count ----------------
__global__ void k_count(const int* __restrict__ dst, int* __restrict__ cnt) {
    int e = blockIdx.x * blockDim.x + threadIdx.x;
    if (e < N_EDGES) atomicAdd(&cnt[dst[e]], 1);
}

__global__ void k_dinv(const int* __restrict__ cnt, float* __restrict__ dinv) {
    int n = blockIdx.x * blockDim.x + threadIdx.x;
    if (n < N_NODES) dinv[n] = rsqrtf((float)cnt[n] + 1.0f);  // +1 self-loop
}

// ---------------- exclusive scan of cnt -> off (3 phases) ----------------
__global__ void k_scan_partial(const int* __restrict__ cnt, int* __restrict__ bsum) {
    __shared__ int sdata[256];
    int b = blockIdx.x, t = threadIdx.x;
    int base = b * SCAN_CHUNK;
    int sum = 0;
    for (int i = t; i < SCAN_CHUNK; i += 256) {
        int idx = base + i;
        sum += (idx < N_NODES) ? cnt[idx] : 0;
    }
    sdata[t] = sum;
    __syncthreads();
    for (int s = 128; s > 0; s >>= 1) {
        if (t < s) sdata[t] += sdata[t + s];
        __syncthreads();
    }
    if (t == 0) bsum[b] = sdata[0];
}

__global__ void k_scan_bsum(int* __restrict__ bsum) {
    if (threadIdx.x == 0 && blockIdx.x == 0) {
        int run = 0;
        for (int i = 0; i < N_CHUNKS; ++i) { int v = bsum[i]; bsum[i] = run; run += v; }
    }
}

__global__ void k_scan_final(const int* __restrict__ cnt, const int* __restrict__ bsum,
                             int* __restrict__ off, int* __restrict__ cur) {
    __shared__ int tsum[256];
    int b = blockIdx.x, t = threadIdx.x;
    int base = b * SCAN_CHUNK;
    int v[4]; int local = 0;
    #pragma unroll
    for (int i = 0; i < 4; ++i) {
        int idx = base + t * 4 + i;
        v[i] = (idx < N_NODES) ? cnt[idx] : 0;
        local += v[i];
    }
    tsum[t] = local;
    __syncthreads();
    for (int ofs = 1; ofs < 256; ofs <<= 1) {
        int y = (t >= ofs) ? tsum[t - ofs] : 0;
        __syncthreads();
        tsum[t] += y;
        __syncthreads();
    }
    int run = bsum[b] + tsum[t] - local;  // exclusive prefix for this thread
    #pragma unroll
    for (int i = 0; i < 4; ++i) {
        int idx = base + t * 4 + i;
        if (idx < N_NODES) { off[idx] = run; cur[idx] = run; }
        run += v[i];
    }
    if (b == 0 && t == 0) off[N_NODES] = N_EDGES;
}

// ---------------- scatter edges into CSR order (packed src + dinv[src]) ----------------
__global__ void k_scatter(const int* __restrict__ src, const int* __restrict__ dst,
                          int* __restrict__ cur, int2* __restrict__ edges,
                          const float* __restrict__ dinv) {
    int e = blockIdx.x * blockDim.x + threadIdx.x;
    if (e < N_EDGES) {
        int d = dst[e];
        int s = src[e];
        int p = atomicAdd(&cur[d], 1);
        edges[p] = make_int2(s, __float_as_int(dinv[s]));
    }
}

// ---------------- GEMM1: x[N,256] @ W1[256,128] -> h[N,128] (f32) ----------------
#define G1_BM 64
#define G1_BN 128
#define G1_BK 32
__global__ __launch_bounds__(256) void k_gemm1(const float* __restrict__ A,
                                               const float* __restrict__ B,
                                               float* __restrict__ C) {
    __shared__ float As[G1_BM][G1_BK + 4];
    __shared__ float Bs[G1_BK][G1_BN];
    int t = threadIdx.x;
    int tx = t & 31;   // cols tx*4 .. +3 (128)
    int ty = t >> 5;   // rows ty*8 .. +7 (64)
    int row0 = blockIdx.x * G1_BM;
    float acc[8][4] = {};
    for (int k0 = 0; k0 < F_IN; k0 += G1_BK) {
        #pragma unroll
        for (int i = 0; i < 2; ++i) {
            int idx = t + i * 256;
            int r = idx >> 3, v = idx & 7;
            int gr = row0 + r; if (gr > N_NODES - 1) gr = N_NODES - 1;
            float4 va = *(const float4*)(A + (size_t)gr * F_IN + k0 + v * 4);
            *(float4*)(&As[r][v * 4]) = va;
        }
        #pragma unroll
        for (int i = 0; i < 4; ++i) {
            int idx = t + i * 256;
            int kk = idx >> 5, v = idx & 31;
            float4 vb = *(const float4*)(B + (size_t)(k0 + kk) * F_HID + v * 4);
            *(float4*)(&Bs[kk][v * 4]) = vb;
        }
        __syncthreads();
        #pragma unroll
        for (int kk = 0; kk < G1_BK; ++kk) {
            float4 b4 = *(const float4*)(&Bs[kk][tx * 4]);
            float b[4] = {b4.x, b4.y, b4.z, b4.w};
            float a[8];
            #pragma unroll
            for (int i = 0; i < 8; ++i) a[i] = As[ty * 8 + i][kk];
            #pragma unroll
            for (int i = 0; i < 8; ++i)
                #pragma unroll
                for (int j = 0; j < 4; ++j) acc[i][j] += a[i] * b[j];
        }
        __syncthreads();
    }
    #pragma unroll
    for (int i = 0; i < 8; ++i) {
        int gr = row0 + ty * 8 + i;
        if (gr < N_NODES) {
            float4 vo = make_float4(acc[i][0], acc[i][1], acc[i][2], acc[i][3]);
            *(float4*)(C + (size_t)gr * F_HID + tx * 4) = vo;
        }
    }
}

// ---------------- agg1: h1 = relu(D^-1/2 A D^-1/2 h + b1) ----------------
// 32 lanes per node (float4 each = 128 feats), 8 nodes per 256-thread block.
// Edge loop unrolled x4: independent gathers in flight to hide latency.
__global__ __launch_bounds__(256) void k_agg1(const float* __restrict__ h_,
                                              const int* __restrict__ off,
                                              const int2* __restrict__ edges,
                                              const float* __restrict__ dinv,
                                              const float* __restrict__ b1,
                                              float* __restrict__ h1_) {
    const float4* h = (const float4*)h_;
    float4* h1 = (float4*)h1_;
    int node = blockIdx.x * 8 + (threadIdx.x >> 5);
    int f4 = threadIdx.x & 31;
    if (node >= N_NODES) return;
    int s0 = off[node], s1 = off[node + 1];
    float dn = dinv[node];
    float4 acc = h[(size_t)node * 32 + f4];
    acc.x *= dn; acc.y *= dn; acc.z *= dn; acc.w *= dn;
    int e = s0;
    for (; e + 4 <= s1; e += 4) {
        int2 e0 = edges[e], e1 = edges[e + 1], e2 = edges[e + 2], e3 = edges[e + 3];
        float4 v0 = h[(size_t)e0.x * 32 + f4];
        float4 v1 = h[(size_t)e1.x * 32 + f4];
        float4 v2 = h[(size_t)e2.x * 32 + f4];
        float4 v3 = h[(size_t)e3.x * 32 + f4];
        float w0 = __int_as_float(e0.y), w1 = __int_as_float(e1.y);
        float w2 = __int_as_float(e2.y), w3 = __int_as_float(e3.y);
        acc.x += w0 * v0.x + w1 * v1.x + w2 * v2.x + w3 * v3.x;
        acc.y += w0 * v0.y + w1 * v1.y + w2 * v2.y + w3 * v3.y;
        acc.z += w0 * v0.z + w1 * v1.z + w2 * v2.z + w3 * v3.z;
        acc.w += w0 * v0.w + w1 * v1.w + w2 * v2.w + w3 * v3.w;
    }
    for (; e < s1; ++e) {
        int2 e0 = edges[e];
        float4 v0 = h[(size_t)e0.x * 32 + f4];
        float w0 = __int_as_float(e0.y);
        acc.x += w0 * v0.x; acc.y += w0 * v0.y;
        acc.z += w0 * v0.z; acc.w += w0 * v0.w;
    }
    float4 bb = ((const float4*)b1)[f4];
    float4 r;
    r.x = fmaxf(acc.x * dn + bb.x, 0.0f);
    r.y = fmaxf(acc.y * dn + bb.y, 0.0f);
    r.z = fmaxf(acc.z * dn + bb.z, 0.0f);
    r.w = fmaxf(acc.w * dn + bb.w, 0.0f);
    h1[(size_t)node * 32 + f4] = r;
}

// ---------------- GEMM2: h1[N,128] @ W2[128,40] -> h2[N,40] ----------------
#define G2_BM 64
#define G2_BN 64
#define G2_BK 32
__global__ __launch_bounds__(256) void k_gemm2(const float* __restrict__ A,
                                               const float* __restrict__ B,
                                               float* __restrict__ C) {
    __shared__ float As[G2_BM][G2_BK + 4];
    __shared__ float Bs[G2_BK][G2_BN];
    int t = threadIdx.x;
    int tx = t & 15;
    int ty = t >> 4;
    int row0 = blockIdx.x * G2_BM;
    float acc[4][4] = {};
    for (int k0 = 0; k0 < F_HID; k0 += G2_BK) {
        #pragma unroll
        for (int i = 0; i < 2; ++i) {
            int idx = t + i * 256;
            int r = idx >> 3, v = idx & 7;
            int gr = row0 + r; if (gr > N_NODES - 1) gr = N_NODES - 1;
            float4 va = *(const float4*)(A + (size_t)gr * F_HID + k0 + v * 4);
            *(float4*)(&As[r][v * 4]) = va;
        }
        #pragma unroll
        for (int i = 0; i < 2; ++i) {
            int idx = t + i * 256;
            int kk = idx >> 4, v = idx & 15;
            float4 vb = make_float4(0.f, 0.f, 0.f, 0.f);
            if (v * 4 < F_OUT)
                vb = *(const float4*)(B + (size_t)(k0 + kk) * F_OUT + v * 4);
            *(float4*)(&Bs[kk][v * 4]) = vb;
        }
        __syncthreads();
        #pragma unroll
        for (int kk = 0; kk < G2_BK; ++kk) {
            float4 b4 = *(const float4*)(&Bs[kk][tx * 4]);
            float b[4] = {b4.x, b4.y, b4.z, b4.w};
            float a[4];
            #pragma unroll
            for (int i = 0; i < 4; ++i) a[i] = As[ty * 4 + i][kk];
            #pragma unroll
            for (int i = 0; i < 4; ++i)
                #pragma unroll
                for (int j = 0; j < 4; ++j) acc[i][j] += a[i] * b[j];
        }
        __syncthreads();
    }
    #pragma unroll
    for (int i = 0; i < 4; ++i) {
        int gr = row0 + ty * 4 + i;
        int c0 = tx * 4;
        if (gr < N_NODES && c0 < F_OUT) {
            float4 vo = make_float4(acc[i][0], acc[i][1], acc[i][2], acc[i][3]);
            *(float4*)(C + (size_t)gr * F_OUT + c0) = vo;
        }
    }
}

// ---------------- agg2 + bias + log_softmax (wave per node, unroll x4) ----------------
// h2 is padded by 64 floats so lanes 40..63 can load unguarded (no divergence).
__global__ __launch_bounds__(256) void k_agg2(const float* __restrict__ h2,
                                              const int* __restrict__ off,
                                              const int2* __restrict__ edges,
                                              const float* __restrict__ dinv,
                                              const float* __restrict__ b2,
                                              float* __restrict__ out) {
    int node = blockIdx.x * 4 + (threadIdx.x >> 6);
    int lane = threadIdx.x & 63;
    if (node >= N_NODES) return;
    int s0 = off[node], s1 = off[node + 1];
    float dn = dinv[node];
    float acc = dn * h2[(size_t)node * F_OUT + lane];
    int e = s0;
    for (; e + 4 <= s1; e += 4) {
        int2 e0 = edges[e], e1 = edges[e + 1], e2 = edges[e + 2], e3 = edges[e + 3];
        float v0 = h2[(size_t)e0.x * F_OUT + lane];
        float v1 = h2[(size_t)e1.x * F_OUT + lane];
        float v2 = h2[(size_t)e2.x * F_OUT + lane];
        float v3 = h2[(size_t)e3.x * F_OUT + lane];
        acc += __int_as_float(e0.y) * v0 + __int_as_float(e1.y) * v1
             + __int_as_float(e2.y) * v2 + __int_as_float(e3.y) * v3;
    }
    for (; e < s1; ++e) {
        int2 e0 = edges[e];
        acc += __int_as_float(e0.y) * h2[(size_t)e0.x * F_OUT + lane];
    }
    float v = (lane < F_OUT) ? (acc * dn + b2[lane]) : -3.4e38f;
    float m = v;
    #pragma unroll
    for (int o = 32; o > 0; o >>= 1) m = fmaxf(m, __shfl_xor(m, o));
    float ex = (lane < F_OUT) ? __expf(v - m) : 0.0f;
    float s = ex;
    #pragma unroll
    for (int o = 32; o > 0; o >>= 1) s += __shfl_xor(s, o);
    float ls = __logf(s);
    if (lane < F_OUT) out[(size_t)node * F_OUT + lane] = v - m - ls;
}

// ---------------- launch ----------------
static inline char* alignup(char* p) {
    return (char*)(((uintptr_t)p + 255) & ~(uintptr_t)255);
}

extern "C" void kernel_launch(void* const* d_in, const int* in_sizes, int n_in,
                              void* d_out, int out_size, void* d_ws, size_t ws_size,
                              hipStream_t stream) {
    const float* x  = (const float*)d_in[0];
    const int*   ei = (const int*)d_in[1];
    const float* W1 = (const float*)d_in[2];
    const float* b1 = (const float*)d_in[3];
    const float* W2 = (const float*)d_in[4];
    const float* b2 = (const float*)d_in[5];
    float* out = (float*)d_out;

    char* w = (char*)d_ws;
    int* cnt   = (int*)w;          w = alignup(w + (size_t)N_NODES * 4);
    int* off   = (int*)w;          w = alignup(w + (size_t)(N_NODES + 1) * 4);
    int* cur   = (int*)w;          w = alignup(w + (size_t)N_NODES * 4);
    int2* edges = (int2*)w;        w = alignup(w + (size_t)N_EDGES * 8);
    int* bsum  = (int*)w;          w = alignup(w + (size_t)N_CHUNKS * 4);
    float* dinv = (float*)w;       w = alignup(w + (size_t)N_NODES * 4);
    float* h    = (float*)w;       w = alignup(w + (size_t)N_NODES * F_HID * 4);
    float* h1   = (float*)w;       w = alignup(w + (size_t)N_NODES * F_HID * 4);
    float* h2   = (float*)w;       w = alignup(w + ((size_t)N_NODES * F_OUT + 64) * 4);

    const int* srcp = ei;
    const int* dstp = ei + N_EDGES;

    hipMemsetAsync(cnt, 0, (size_t)N_NODES * 4, stream);
    k_count<<<(N_EDGES + 255) / 256, 256, 0, stream>>>(dstp, cnt);
    k_dinv<<<(N_NODES + 255) / 256, 256, 0, stream>>>(cnt, dinv);
    k_scan_partial<<<N_CHUNKS, 256, 0, stream>>>(cnt, bsum);
    k_scan_bsum<<<1, 64, 0, stream>>>(bsum);
    k_scan_final<<<N_CHUNKS, 256, 0, stream>>>(cnt, bsum, off, cur);
    k_scatter<<<(N_EDGES + 255) / 256, 256, 0, stream>>>(srcp, dstp, cur, edges, dinv);

    k_gemm1<<<(N_NODES + G1_BM - 1) / G1_BM, 256, 0, stream>>>(x, W1, h);
    k_agg1<<<(N_NODES + 7) / 8, 256, 0, stream>>>(h, off, edges, dinv, b1, h1);
    k_gemm2<<<(N_NODES + G2_BM - 1) / G2_BM, 256, 0, stream>>>(h1, W2, h2);
    k_agg2<<<(N_NODES + 3) / 4, 256, 0, stream>>>(h2, off, edges, dinv, b2, out);
}

// Round 3
// 492.794 us; speedup vs baseline: 1.8077x; 1.2150x over previous
//
#include <hip/hip_runtime.h>
#include <cstdint>
#include <cstddef>

#define N_NODES 100000
#define N_EDGES 1600000
#define F_IN 256
#define F_HID 128
#define F_OUT 40
#define F_OUT_P 64   // h2 padded cols (bf16)

#define SCAN_CHUNK 1024
#define N_CHUNKS ((N_NODES + SCAN_CHUNK - 1) / SCAN_CHUNK)  // 98

typedef __attribute__((ext_vector_type(8))) short short8;
typedef __attribute__((ext_vector_type(4))) float floatx4;

__device__ __forceinline__ float bf2f(unsigned short u) {
    return __uint_as_float(((unsigned int)u) << 16);
}
__device__ __forceinline__ unsigned short f2bf(float f) {
    unsigned int x = __float_as_uint(f);
    x += 0x7fffu + ((x >> 16) & 1u);   // RNE
    return (unsigned short)(x >> 16);
}

// ---------------- degree count ----------------
__global__ void k_count(const int* __restrict__ dst, int* __restrict__ cnt) {
    int e = blockIdx.x * blockDim.x + threadIdx.x;
    if (e < N_EDGES) atomicAdd(&cnt[dst[e]], 1);
}

__global__ void k_dinv(const int* __restrict__ cnt, float* __restrict__ dinv) {
    int n = blockIdx.x * blockDim.x + threadIdx.x;
    if (n < N_NODES) dinv[n] = rsqrtf((float)cnt[n] + 1.0f);  // +1 self-loop
}

// ---------------- exclusive scan of cnt -> off ----------------
__global__ void k_scan_partial(const int* __restrict__ cnt, int* __restrict__ bsum) {
    __shared__ int sdata[256];
    int b = blockIdx.x, t = threadIdx.x;
    int base = b * SCAN_CHUNK;
    int sum = 0;
    for (int i = t; i < SCAN_CHUNK; i += 256) {
        int idx = base + i;
        sum += (idx < N_NODES) ? cnt[idx] : 0;
    }
    sdata[t] = sum;
    __syncthreads();
    for (int s = 128; s > 0; s >>= 1) {
        if (t < s) sdata[t] += sdata[t + s];
        __syncthreads();
    }
    if (t == 0) bsum[b] = sdata[0];
}

__global__ void k_scan_bsum(int* __restrict__ bsum) {
    if (threadIdx.x == 0 && blockIdx.x == 0) {
        int run = 0;
        for (int i = 0; i < N_CHUNKS; ++i) { int v = bsum[i]; bsum[i] = run; run += v; }
    }
}

__global__ void k_scan_final(const int* __restrict__ cnt, const int* __restrict__ bsum,
                             int* __restrict__ off, int* __restrict__ cur) {
    __shared__ int tsum[256];
    int b = blockIdx.x, t = threadIdx.x;
    int base = b * SCAN_CHUNK;
    int v[4]; int local = 0;
    #pragma unroll
    for (int i = 0; i < 4; ++i) {
        int idx = base + t * 4 + i;
        v[i] = (idx < N_NODES) ? cnt[idx] : 0;
        local += v[i];
    }
    tsum[t] = local;
    __syncthreads();
    for (int ofs = 1; ofs < 256; ofs <<= 1) {
        int y = (t >= ofs) ? tsum[t - ofs] : 0;
        __syncthreads();
        tsum[t] += y;
        __syncthreads();
    }
    int run = bsum[b] + tsum[t] - local;
    #pragma unroll
    for (int i = 0; i < 4; ++i) {
        int idx = base + t * 4 + i;
        if (idx < N_NODES) { off[idx] = run; cur[idx] = run; }
        run += v[i];
    }
    if (b == 0 && t == 0) off[N_NODES] = N_EDGES;
}

// ---------------- scatter edges into CSR order (packed src + dinv[src]) ----------------
__global__ void k_scatter(const int* __restrict__ src, const int* __restrict__ dst,
                          int* __restrict__ cur, int2* __restrict__ edges,
                          const float* __restrict__ dinv) {
    int e = blockIdx.x * blockDim.x + threadIdx.x;
    if (e < N_EDGES) {
        int d = dst[e];
        int s = src[e];
        int p = atomicAdd(&cur[d], 1);
        edges[p] = make_int2(s, __float_as_int(dinv[s]));
    }
}

// ---------------- weight conversion ----------------
// W1 [256,128] f32 -> W1t [128][256] bf16
__global__ void k_convW1(const float* __restrict__ W1, unsigned short* __restrict__ W1t) {
    int i = blockIdx.x * blockDim.x + threadIdx.x;
    if (i < F_IN * F_HID) {
        int k = i >> 7, n = i & 127;
        W1t[n * F_IN + k] = f2bf(W1[i]);
    }
}
// W2 [128,40] f32 -> W2t [64][128] bf16, zero-padded rows 40..63
__global__ void k_convW2(const float* __restrict__ W2, unsigned short* __restrict__ W2t) {
    int i = blockIdx.x * blockDim.x + threadIdx.x;
    if (i < F_OUT_P * F_HID) {
        int k = i >> 6, n = i & 63;
        float v = (n < F_OUT) ? W2[k * F_OUT + n] : 0.0f;
        W2t[n * F_HID + k] = f2bf(v);
    }
}

// ---------------- GEMM1 (MFMA bf16): x[N,256]f32 @ W1 -> h[N,128]bf16 ----------------
// block 256 = 4 waves; tile 128 rows x 128 cols; wave w: rows w*32..+31 (2 rowtiles x16),
// 8 coltiles x16. K staged 32 at a time; x converted f32->bf16 during staging.
__global__ __launch_bounds__(256) void k_gemm1(const float* __restrict__ A,
                                               const unsigned short* __restrict__ Wt,
                                               unsigned short* __restrict__ C) {
    __shared__ unsigned short As[128][40];  // pad 40: 80B row stride, 2-way max
    __shared__ unsigned short Ws[128][40];
    int t = threadIdx.x;
    int wave = t >> 6, lane = t & 63;
    int quad = lane >> 4, l16 = lane & 15;
    int row0 = blockIdx.x * 128;
    floatx4 acc[2][8];
    #pragma unroll
    for (int i = 0; i < 2; ++i)
        #pragma unroll
        for (int j = 0; j < 8; ++j)
            #pragma unroll
            for (int r = 0; r < 4; ++r) acc[i][j][r] = 0.0f;

    for (int k0 = 0; k0 < F_IN; k0 += 32) {
        // stage A: 128 rows x 32 cols f32 -> bf16
        #pragma unroll
        for (int i = 0; i < 4; ++i) {
            int idx = t + i * 256;          // 0..1023
            int r = idx >> 3, c = idx & 7;  // c*4 in [0,28]
            int gr = row0 + r; if (gr > N_NODES - 1) gr = N_NODES - 1;
            float4 va = *(const float4*)(A + (size_t)gr * F_IN + k0 + c * 4);
            ushort4 u;
            u.x = f2bf(va.x); u.y = f2bf(va.y); u.z = f2bf(va.z); u.w = f2bf(va.w);
            *(ushort4*)(&As[r][c * 4]) = u;
        }
        // stage Wt: 128 rows x 32 cols bf16
        #pragma unroll
        for (int i = 0; i < 2; ++i) {
            int idx = t + i * 256;          // 0..511
            int n = idx >> 2, c = idx & 3;  // c*8 in [0,24]
            ushort4 w0 = *(const ushort4*)(Wt + (size_t)n * F_IN + k0 + c * 8);
            ushort4 w1 = *(const ushort4*)(Wt + (size_t)n * F_IN + k0 + c * 8 + 4);
            *(ushort4*)(&Ws[n][c * 8]) = w0;
            *(ushort4*)(&Ws[n][c * 8 + 4]) = w1;
        }
        __syncthreads();
        short8 af[2];
        #pragma unroll
        for (int rt = 0; rt < 2; ++rt)
            af[rt] = *(const short8*)(&As[wave * 32 + rt * 16 + l16][quad * 8]);
        #pragma unroll
        for (int ct = 0; ct < 8; ++ct) {
            short8 bf = *(const short8*)(&Ws[ct * 16 + l16][quad * 8]);
            acc[0][ct] = __builtin_amdgcn_mfma_f32_16x16x32_bf16(af[0], bf, acc[0][ct], 0, 0, 0);
            acc[1][ct] = __builtin_amdgcn_mfma_f32_16x16x32_bf16(af[1], bf, acc[1][ct], 0, 0, 0);
        }
        __syncthreads();
    }
    // epilogue: D col=l16, row=quad*4+r
    #pragma unroll
    for (int rt = 0; rt < 2; ++rt) {
        #pragma unroll
        for (int ct = 0; ct < 8; ++ct) {
            #pragma unroll
            for (int r = 0; r < 4; ++r) {
                int row = row0 + wave * 32 + rt * 16 + quad * 4 + r;
                if (row < N_NODES)
                    C[(size_t)row * F_HID + ct * 16 + l16] = f2bf(acc[rt][ct][r]);
            }
        }
    }
}

// ---------------- agg1: h1 = relu(D^-1/2 A D^-1/2 h + b1), bf16 in/out ----------------
__global__ __launch_bounds__(256) void k_agg1(const unsigned short* __restrict__ h_,
                                              const int* __restrict__ off,
                                              const int2* __restrict__ edges,
                                              const float* __restrict__ dinv,
                                              const float* __restrict__ b1,
                                              unsigned short* __restrict__ h1_) {
    const ushort4* h = (const ushort4*)h_;   // row = 32 ushort4
    ushort4* h1 = (ushort4*)h1_;
    int node = blockIdx.x * 8 + (threadIdx.x >> 5);
    int f4 = threadIdx.x & 31;
    if (node >= N_NODES) return;
    int s0 = off[node], s1 = off[node + 1];
    float dn = dinv[node];
    ushort4 sv = h[(size_t)node * 32 + f4];
    float ax = dn * bf2f(sv.x), ay = dn * bf2f(sv.y), az = dn * bf2f(sv.z), aw = dn * bf2f(sv.w);
    int e = s0;
    for (; e + 4 <= s1; e += 4) {
        int2 e0 = edges[e], e1 = edges[e + 1], e2 = edges[e + 2], e3 = edges[e + 3];
        ushort4 v0 = h[(size_t)e0.x * 32 + f4];
        ushort4 v1 = h[(size_t)e1.x * 32 + f4];
        ushort4 v2 = h[(size_t)e2.x * 32 + f4];
        ushort4 v3 = h[(size_t)e3.x * 32 + f4];
        float w0 = __int_as_float(e0.y), w1 = __int_as_float(e1.y);
        float w2 = __int_as_float(e2.y), w3 = __int_as_float(e3.y);
        ax += w0 * bf2f(v0.x) + w1 * bf2f(v1.x) + w2 * bf2f(v2.x) + w3 * bf2f(v3.x);
        ay += w0 * bf2f(v0.y) + w1 * bf2f(v1.y) + w2 * bf2f(v2.y) + w3 * bf2f(v3.y);
        az += w0 * bf2f(v0.z) + w1 * bf2f(v1.z) + w2 * bf2f(v2.z) + w3 * bf2f(v3.z);
        aw += w0 * bf2f(v0.w) + w1 * bf2f(v1.w) + w2 * bf2f(v2.w) + w3 * bf2f(v3.w);
    }
    for (; e < s1; ++e) {
        int2 e0 = edges[e];
        ushort4 v0 = h[(size_t)e0.x * 32 + f4];
        float w0 = __int_as_float(e0.y);
        ax += w0 * bf2f(v0.x); ay += w0 * bf2f(v0.y);
        az += w0 * bf2f(v0.z); aw += w0 * bf2f(v0.w);
    }
    float4 bb = ((const float4*)b1)[f4];
    ushort4 r;
    r.x = f2bf(fmaxf(ax * dn + bb.x, 0.0f));
    r.y = f2bf(fmaxf(ay * dn + bb.y, 0.0f));
    r.z = f2bf(fmaxf(az * dn + bb.z, 0.0f));
    r.w = f2bf(fmaxf(aw * dn + bb.w, 0.0f));
    h1[(size_t)node * 32 + f4] = r;
}

// ---------------- GEMM2 (MFMA bf16): h1[N,128]bf16 @ W2 -> h2[N,64]bf16 ----------------
// tile 128 rows x 64 cols, K=128 staged once. Cols 40..63 are zero (padded W2t).
__global__ __launch_bounds__(256) void k_gemm2(const unsigned short* __restrict__ A,
                                               const unsigned short* __restrict__ Wt,
                                               unsigned short* __restrict__ C) {
    __shared__ unsigned short As[128][136];  // 272B rows, 16B aligned, 2-way max
    __shared__ unsigned short Ws[64][136];
    int t = threadIdx.x;
    int wave = t >> 6, lane = t & 63;
    int quad = lane >> 4, l16 = lane & 15;
    int row0 = blockIdx.x * 128;
    floatx4 acc[2][4];
    #pragma unroll
    for (int i = 0; i < 2; ++i)
        #pragma unroll
        for (int j = 0; j < 4; ++j)
            #pragma unroll
            for (int r = 0; r < 4; ++r) acc[i][j][r] = 0.0f;

    // stage A: 128 rows x 128 bf16
    #pragma unroll
    for (int i = 0; i < 8; ++i) {
        int idx = t + i * 256;           // 0..2047
        int r = idx >> 4, c = idx & 15;  // c*8 in [0,120]
        int gr = row0 + r; if (gr > N_NODES - 1) gr = N_NODES - 1;
        ushort4 w0 = *(const ushort4*)(A + (size_t)gr * F_HID + c * 8);
        ushort4 w1 = *(const ushort4*)(A + (size_t)gr * F_HID + c * 8 + 4);
        *(ushort4*)(&As[r][c * 8]) = w0;
        *(ushort4*)(&As[r][c * 8 + 4]) = w1;
    }
    // stage Wt: 64 rows x 128 bf16
    #pragma unroll
    for (int i = 0; i < 4; ++i) {
        int idx = t + i * 256;           // 0..1023
        int n = idx >> 4, c = idx & 15;
        ushort4 w0 = *(const ushort4*)(Wt + (size_t)n * F_HID + c * 8);
        ushort4 w1 = *(const ushort4*)(Wt + (size_t)n * F_HID + c * 8 + 4);
        *(ushort4*)(&Ws[n][c * 8]) = w0;
        *(ushort4*)(&Ws[n][c * 8 + 4]) = w1;
    }
    __syncthreads();
    #pragma unroll
    for (int ks = 0; ks < 4; ++ks) {
        int k0 = ks * 32;
        short8 af[2];
        #pragma unroll
        for (int rt = 0; rt < 2; ++rt)
            af[rt] = *(const short8*)(&As[wave * 32 + rt * 16 + l16][k0 + quad * 8]);
        #pragma unroll
        for (int ct = 0; ct < 4; ++ct) {
            short8 bf = *(const short8*)(&Ws[ct * 16 + l16][k0 + quad * 8]);
            acc[0][ct] = __builtin_amdgcn_mfma_f32_16x16x32_bf16(af[0], bf, acc[0][ct], 0, 0, 0);
            acc[1][ct] = __builtin_amdgcn_mfma_f32_16x16x32_bf16(af[1], bf, acc[1][ct], 0, 0, 0);
        }
    }
    #pragma unroll
    for (int rt = 0; rt < 2; ++rt) {
        #pragma unroll
        for (int ct = 0; ct < 4; ++ct) {
            #pragma unroll
            for (int r = 0; r < 4; ++r) {
                int row = row0 + wave * 32 + rt * 16 + quad * 4 + r;
                if (row < N_NODES)
                    C[(size_t)row * F_OUT_P + ct * 16 + l16] = f2bf(acc[rt][ct][r]);
            }
        }
    }
}

// ---------------- agg2 + bias + log_softmax (wave per node, unroll x4) ----------------
__global__ __launch_bounds__(256) void k_agg2(const unsigned short* __restrict__ h2,
                                              const int* __restrict__ off,
                                              const int2* __restrict__ edges,
                                              const float* __restrict__ dinv,
                                              const float* __restrict__ b2,
                                              float* __restrict__ out) {
    int node = blockIdx.x * 4 + (threadIdx.x >> 6);
    int lane = threadIdx.x & 63;
    if (node >= N_NODES) return;
    int s0 = off[node], s1 = off[node + 1];
    float dn = dinv[node];
    float acc = dn * bf2f(h2[(size_t)node * F_OUT_P + lane]);
    int e = s0;
    for (; e + 4 <= s1; e += 4) {
        int2 e0 = edges[e], e1 = edges[e + 1], e2 = edges[e + 2], e3 = edges[e + 3];
        float v0 = bf2f(h2[(size_t)e0.x * F_OUT_P + lane]);
        float v1 = bf2f(h2[(size_t)e1.x * F_OUT_P + lane]);
        float v2 = bf2f(h2[(size_t)e2.x * F_OUT_P + lane]);
        float v3 = bf2f(h2[(size_t)e3.x * F_OUT_P + lane]);
        acc += __int_as_float(e0.y) * v0 + __int_as_float(e1.y) * v1
             + __int_as_float(e2.y) * v2 + __int_as_float(e3.y) * v3;
    }
    for (; e < s1; ++e) {
        int2 e0 = edges[e];
        acc += __int_as_float(e0.y) * bf2f(h2[(size_t)e0.x * F_OUT_P + lane]);
    }
    float v = (lane < F_OUT) ? (acc * dn + b2[lane]) : -3.4e38f;
    float m = v;
    #pragma unroll
    for (int o = 32; o > 0; o >>= 1) m = fmaxf(m, __shfl_xor(m, o));
    float ex = (lane < F_OUT) ? __expf(v - m) : 0.0f;
    float s = ex;
    #pragma unroll
    for (int o = 32; o > 0; o >>= 1) s += __shfl_xor(s, o);
    float ls = __logf(s);
    if (lane < F_OUT) out[(size_t)node * F_OUT + lane] = v - m - ls;
}

// ---------------- launch ----------------
static inline char* alignup(char* p) {
    return (char*)(((uintptr_t)p + 255) & ~(uintptr_t)255);
}

extern "C" void kernel_launch(void* const* d_in, const int* in_sizes, int n_in,
                              void* d_out, int out_size, void* d_ws, size_t ws_size,
                              hipStream_t stream) {
    const float* x  = (const float*)d_in[0];
    const int*   ei = (const int*)d_in[1];
    const float* W1 = (const float*)d_in[2];
    const float* b1 = (const float*)d_in[3];
    const float* W2 = (const float*)d_in[4];
    const float* b2 = (const float*)d_in[5];
    float* out = (float*)d_out;

    char* w = (char*)d_ws;
    int* cnt   = (int*)w;             w = alignup(w + (size_t)N_NODES * 4);
    int* off   = (int*)w;             w = alignup(w + (size_t)(N_NODES + 1) * 4);
    int* cur   = (int*)w;             w = alignup(w + (size_t)N_NODES * 4);
    int2* edges = (int2*)w;           w = alignup(w + (size_t)N_EDGES * 8);
    int* bsum  = (int*)w;             w = alignup(w + (size_t)N_CHUNKS * 4);
    float* dinv = (float*)w;          w = alignup(w + (size_t)N_NODES * 4);
    unsigned short* W1t = (unsigned short*)w;  w = alignup(w + (size_t)F_HID * F_IN * 2);
    unsigned short* W2t = (unsigned short*)w;  w = alignup(w + (size_t)F_OUT_P * F_HID * 2);
    unsigned short* h   = (unsigned short*)w;  w = alignup(w + (size_t)N_NODES * F_HID * 2);
    unsigned short* h1  = (unsigned short*)w;  w = alignup(w + (size_t)N_NODES * F_HID * 2);
    unsigned short* h2  = (unsigned short*)w;  w = alignup(w + (size_t)N_NODES * F_OUT_P * 2);

    const int* srcp = ei;
    const int* dstp = ei + N_EDGES;

    hipMemsetAsync(cnt, 0, (size_t)N_NODES * 4, stream);
    k_count<<<(N_EDGES + 255) / 256, 256, 0, stream>>>(dstp, cnt);
    k_dinv<<<(N_NODES + 255) / 256, 256, 0, stream>>>(cnt, dinv);
    k_scan_partial<<<N_CHUNKS, 256, 0, stream>>>(cnt, bsum);
    k_scan_bsum<<<1, 64, 0, stream>>>(bsum);
    k_scan_final<<<N_CHUNKS, 256, 0, stream>>>(cnt, bsum, off, cur);
    k_scatter<<<(N_EDGES + 255) / 256, 256, 0, stream>>>(srcp, dstp, cur, edges, dinv);

    k_convW1<<<(F_IN * F_HID + 255) / 256, 256, 0, stream>>>(W1, W1t);
    k_convW2<<<(F_OUT_P * F_HID + 255) / 256, 256, 0, stream>>>(W2, W2t);

    k_gemm1<<<(N_NODES + 127) / 128, 256, 0, stream>>>(x, W1t, h);
    k_agg1<<<(N_NODES + 7) / 8, 256, 0, stream>>>(h, off, edges, dinv, b1, h1);
    k_gemm2<<<(N_NODES + 127) / 128, 256, 0, stream>>>(h1, W2t, h2);
    k_agg2<<<(N_NODES + 3) / 4, 256, 0, stream>>>(h2, off, edges, dinv, b2, out);
}

// Round 4
// 402.694 us; speedup vs baseline: 2.2122x; 1.2237x over previous
//
#include <hip/hip_runtime.h>
#include <cstdint>
#include <cstddef>

#define N_NODES 100000
#define N_EDGES 1600000
#define F_IN 256
#define F_HID 128
#define F_OUT 40
#define F_OUT_P 64   // h2 padded cols (bf16)

#define BKT_SHIFT 8
#define BKT_SIZE 256
#define NBKT ((N_NODES + BKT_SIZE - 1) / BKT_SIZE)   // 391
#define P1_EPT 16
#define P1_EPB (256 * P1_EPT)                        // 4096 edges/block
#define P1_NBLK ((N_EDGES + P1_EPB - 1) / P1_EPB)    // 391

typedef __attribute__((ext_vector_type(8))) short short8;
typedef __attribute__((ext_vector_type(4))) float floatx4;

__device__ __forceinline__ float bf2f(unsigned short u) {
    return __uint_as_float(((unsigned int)u) << 16);
}
__device__ __forceinline__ unsigned short f2bf(float f) {
    unsigned int x = __float_as_uint(f);
    x += 0x7fffu + ((x >> 16) & 1u);   // RNE
    return (unsigned short)(x >> 16);
}

// ---------------- P1a: bucket histogram ----------------
__global__ __launch_bounds__(256) void k_hist(const int* __restrict__ dst,
                                              int* __restrict__ gtot) {
    __shared__ int hist[NBKT];
    for (int i = threadIdx.x; i < NBKT; i += 256) hist[i] = 0;
    __syncthreads();
    int base = blockIdx.x * P1_EPB;
    #pragma unroll
    for (int i = 0; i < P1_EPT; ++i) {
        int e = base + threadIdx.x + i * 256;
        if (e < N_EDGES) atomicAdd(&hist[dst[e] >> BKT_SHIFT], 1);
    }
    __syncthreads();
    for (int i = threadIdx.x; i < NBKT; i += 256)
        if (hist[i]) atomicAdd(&gtot[i], hist[i]);
}

// ---------------- P1b: scan bucket totals ----------------
__global__ __launch_bounds__(256) void k_bktscan(const int* __restrict__ gtot,
                                                 int* __restrict__ boff,
                                                 int* __restrict__ bcur) {
    __shared__ int lds[NBKT + 1];
    int t = threadIdx.x;
    for (int i = t; i < NBKT; i += 256) lds[i] = gtot[i];
    __syncthreads();
    if (t == 0) {
        int run = 0;
        for (int i = 0; i < NBKT; ++i) { int v = lds[i]; lds[i] = run; run += v; }
        lds[NBKT] = run;
    }
    __syncthreads();
    for (int i = t; i <= NBKT; i += 256) {
        boff[i] = lds[i];
        if (i < NBKT) bcur[i] = lds[i];
    }
}

// ---------------- P1c: bin edges by bucket (4B packed records) ----------------
__global__ __launch_bounds__(256) void k_bin(const int* __restrict__ src,
                                             const int* __restrict__ dst,
                                             int* __restrict__ bcur,
                                             unsigned int* __restrict__ binned) {
    __shared__ int hist[NBKT];
    __shared__ int baseg[NBKT];
    __shared__ int cnt2[NBKT];
    for (int i = threadIdx.x; i < NBKT; i += 256) { hist[i] = 0; cnt2[i] = 0; }
    __syncthreads();
    int base = blockIdx.x * P1_EPB;
    int s[P1_EPT], d[P1_EPT];
    #pragma unroll
    for (int i = 0; i < P1_EPT; ++i) {
        int e = base + threadIdx.x + i * 256;
        if (e < N_EDGES) {
            s[i] = src[e]; d[i] = dst[e];
            atomicAdd(&hist[d[i] >> BKT_SHIFT], 1);
        } else d[i] = -1;
    }
    __syncthreads();
    for (int i = threadIdx.x; i < NBKT; i += 256)
        baseg[i] = hist[i] ? atomicAdd(&bcur[i], hist[i]) : 0;
    __syncthreads();
    #pragma unroll
    for (int i = 0; i < P1_EPT; ++i) {
        if (d[i] >= 0) {
            int b = d[i] >> BKT_SHIFT;
            int r = atomicAdd(&cnt2[b], 1);
            binned[baseg[b] + r] =
                (unsigned int)s[i] | ((unsigned int)(d[i] & (BKT_SIZE - 1)) << 17);
        }
    }
}

// ---------------- P2: per-bucket place -> CSR, off[], dinv[] (no global atomics) ----------------
__global__ __launch_bounds__(256) void k_place(const unsigned int* __restrict__ binned,
                                               const int* __restrict__ boff,
                                               int* __restrict__ off,
                                               float* __restrict__ dinv,
                                               int* __restrict__ ssrc) {
    __shared__ int cnt[BKT_SIZE];
    __shared__ int ioff[BKT_SIZE];
    __shared__ int sexcl[BKT_SIZE];
    int b = blockIdx.x, t = threadIdx.x;
    int e0 = boff[b], e1 = boff[b + 1];
    cnt[t] = 0;
    __syncthreads();
    for (int i = e0 + t; i < e1; i += 256)
        atomicAdd(&cnt[binned[i] >> 17], 1);
    __syncthreads();
    int v = cnt[t];
    ioff[t] = v;
    __syncthreads();
    for (int ofs = 1; ofs < 256; ofs <<= 1) {
        int y = (t >= ofs) ? ioff[t - ofs] : 0;
        __syncthreads();
        ioff[t] += y;
        __syncthreads();
    }
    int excl = ioff[t] - v;   // exclusive prefix within bucket
    int n = b * BKT_SIZE + t;
    if (n < N_NODES) {
        off[n] = e0 + excl;
        dinv[n] = rsqrtf((float)v + 1.0f);
    }
    if (b == NBKT - 1 && t == 0) off[N_NODES] = N_EDGES;
    __syncthreads();
    cnt[t] = 0;
    sexcl[t] = excl;
    __syncthreads();
    for (int i = e0 + t; i < e1; i += 256) {
        unsigned int rec = binned[i];
        int dl = rec >> 17;
        int r = atomicAdd(&cnt[dl], 1);
        ssrc[e0 + sexcl[dl] + r] = (int)(rec & 0x1FFFFu);
    }
}

// ---------------- P3: build (src, dinv[src]) records ----------------
__global__ __launch_bounds__(256) void k_mkrec(const int* __restrict__ ssrc,
                                               const float* __restrict__ dinv,
                                               int2* __restrict__ edges) {
    int i = blockIdx.x * blockDim.x + threadIdx.x;   // groups of 4
    if (i < N_EDGES / 4) {
        int4 s4 = ((const int4*)ssrc)[i];
        int4* ep = (int4*)(edges + (size_t)i * 4);
        ep[0] = make_int4(s4.x, __float_as_int(dinv[s4.x]),
                          s4.y, __float_as_int(dinv[s4.y]));
        ep[1] = make_int4(s4.z, __float_as_int(dinv[s4.z]),
                          s4.w, __float_as_int(dinv[s4.w]));
    }
}

// ---------------- weight conversion ----------------
__global__ void k_convW1(const float* __restrict__ W1, unsigned short* __restrict__ W1t) {
    int i = blockIdx.x * blockDim.x + threadIdx.x;
    if (i < F_IN * F_HID) {
        int k = i >> 7, n = i & 127;
        W1t[n * F_IN + k] = f2bf(W1[i]);
    }
}
__global__ void k_convW2(const float* __restrict__ W2, unsigned short* __restrict__ W2t) {
    int i = blockIdx.x * blockDim.x + threadIdx.x;
    if (i < F_OUT_P * F_HID) {
        int k = i >> 6, n = i & 63;
        float v = (n < F_OUT) ? W2[k * F_OUT + n] : 0.0f;
        W2t[n * F_HID + k] = f2bf(v);
    }
}

// ---------------- GEMM1 (MFMA bf16): x[N,256]f32 @ W1 -> h[N,128]bf16 ----------------
__global__ __launch_bounds__(256) void k_gemm1(const float* __restrict__ A,
                                               const unsigned short* __restrict__ Wt,
                                               unsigned short* __restrict__ C) {
    __shared__ unsigned short As[128][40];
    __shared__ unsigned short Ws[128][40];
    int t = threadIdx.x;
    int wave = t >> 6, lane = t & 63;
    int quad = lane >> 4, l16 = lane & 15;
    int row0 = blockIdx.x * 128;
    floatx4 acc[2][8];
    #pragma unroll
    for (int i = 0; i < 2; ++i)
        #pragma unroll
        for (int j = 0; j < 8; ++j)
            #pragma unroll
            for (int r = 0; r < 4; ++r) acc[i][j][r] = 0.0f;

    for (int k0 = 0; k0 < F_IN; k0 += 32) {
        #pragma unroll
        for (int i = 0; i < 4; ++i) {
            int idx = t + i * 256;
            int r = idx >> 3, c = idx & 7;
            int gr = row0 + r; if (gr > N_NODES - 1) gr = N_NODES - 1;
            float4 va = *(const float4*)(A + (size_t)gr * F_IN + k0 + c * 4);
            ushort4 u;
            u.x = f2bf(va.x); u.y = f2bf(va.y); u.z = f2bf(va.z); u.w = f2bf(va.w);
            *(ushort4*)(&As[r][c * 4]) = u;
        }
        #pragma unroll
        for (int i = 0; i < 2; ++i) {
            int idx = t + i * 256;
            int n = idx >> 2, c = idx & 3;
            ushort4 w0 = *(const ushort4*)(Wt + (size_t)n * F_IN + k0 + c * 8);
            ushort4 w1 = *(const ushort4*)(Wt + (size_t)n * F_IN + k0 + c * 8 + 4);
            *(ushort4*)(&Ws[n][c * 8]) = w0;
            *(ushort4*)(&Ws[n][c * 8 + 4]) = w1;
        }
        __syncthreads();
        short8 af[2];
        #pragma unroll
        for (int rt = 0; rt < 2; ++rt)
            af[rt] = *(const short8*)(&As[wave * 32 + rt * 16 + l16][quad * 8]);
        #pragma unroll
        for (int ct = 0; ct < 8; ++ct) {
            short8 bf = *(const short8*)(&Ws[ct * 16 + l16][quad * 8]);
            acc[0][ct] = __builtin_amdgcn_mfma_f32_16x16x32_bf16(af[0], bf, acc[0][ct], 0, 0, 0);
            acc[1][ct] = __builtin_amdgcn_mfma_f32_16x16x32_bf16(af[1], bf, acc[1][ct], 0, 0, 0);
        }
        __syncthreads();
    }
    #pragma unroll
    for (int rt = 0; rt < 2; ++rt) {
        #pragma unroll
        for (int ct = 0; ct < 8; ++ct) {
            #pragma unroll
            for (int r = 0; r < 4; ++r) {
                int row = row0 + wave * 32 + rt * 16 + quad * 4 + r;
                if (row < N_NODES)
                    C[(size_t)row * F_HID + ct * 16 + l16] = f2bf(acc[rt][ct][r]);
            }
        }
    }
}

// ---------------- agg1: h1 = relu(D^-1/2 A D^-1/2 h + b1), bf16 in/out ----------------
__global__ __launch_bounds__(256) void k_agg1(const unsigned short* __restrict__ h_,
                                              const int* __restrict__ off,
                                              const int2* __restrict__ edges,
                                              const float* __restrict__ dinv,
                                              const float* __restrict__ b1,
                                              unsigned short* __restrict__ h1_) {
    const ushort4* h = (const ushort4*)h_;
    ushort4* h1 = (ushort4*)h1_;
    int node = blockIdx.x * 8 + (threadIdx.x >> 5);
    int f4 = threadIdx.x & 31;
    if (node >= N_NODES) return;
    int s0 = off[node], s1 = off[node + 1];
    float dn = dinv[node];
    ushort4 sv = h[(size_t)node * 32 + f4];
    float ax = dn * bf2f(sv.x), ay = dn * bf2f(sv.y), az = dn * bf2f(sv.z), aw = dn * bf2f(sv.w);
    int e = s0;
    for (; e + 4 <= s1; e += 4) {
        int2 e0 = edges[e], e1 = edges[e + 1], e2 = edges[e + 2], e3 = edges[e + 3];
        ushort4 v0 = h[(size_t)e0.x * 32 + f4];
        ushort4 v1 = h[(size_t)e1.x * 32 + f4];
        ushort4 v2 = h[(size_t)e2.x * 32 + f4];
        ushort4 v3 = h[(size_t)e3.x * 32 + f4];
        float w0 = __int_as_float(e0.y), w1 = __int_as_float(e1.y);
        float w2 = __int_as_float(e2.y), w3 = __int_as_float(e3.y);
        ax += w0 * bf2f(v0.x) + w1 * bf2f(v1.x) + w2 * bf2f(v2.x) + w3 * bf2f(v3.x);
        ay += w0 * bf2f(v0.y) + w1 * bf2f(v1.y) + w2 * bf2f(v2.y) + w3 * bf2f(v3.y);
        az += w0 * bf2f(v0.z) + w1 * bf2f(v1.z) + w2 * bf2f(v2.z) + w3 * bf2f(v3.z);
        aw += w0 * bf2f(v0.w) + w1 * bf2f(v1.w) + w2 * bf2f(v2.w) + w3 * bf2f(v3.w);
    }
    for (; e < s1; ++e) {
        int2 e0 = edges[e];
        ushort4 v0 = h[(size_t)e0.x * 32 + f4];
        float w0 = __int_as_float(e0.y);
        ax += w0 * bf2f(v0.x); ay += w0 * bf2f(v0.y);
        az += w0 * bf2f(v0.z); aw += w0 * bf2f(v0.w);
    }
    float4 bb = ((const float4*)b1)[f4];
    ushort4 r;
    r.x = f2bf(fmaxf(ax * dn + bb.x, 0.0f));
    r.y = f2bf(fmaxf(ay * dn + bb.y, 0.0f));
    r.z = f2bf(fmaxf(az * dn + bb.z, 0.0f));
    r.w = f2bf(fmaxf(aw * dn + bb.w, 0.0f));
    h1[(size_t)node * 32 + f4] = r;
}

// ---------------- GEMM2 (MFMA bf16): h1[N,128]bf16 @ W2 -> h2[N,64]bf16 ----------------
__global__ __launch_bounds__(256) void k_gemm2(const unsigned short* __restrict__ A,
                                               const unsigned short* __restrict__ Wt,
                                               unsigned short* __restrict__ C) {
    __shared__ unsigned short As[128][136];
    __shared__ unsigned short Ws[64][136];
    int t = threadIdx.x;
    int wave = t >> 6, lane = t & 63;
    int quad = lane >> 4, l16 = lane & 15;
    int row0 = blockIdx.x * 128;
    floatx4 acc[2][4];
    #pragma unroll
    for (int i = 0; i < 2; ++i)
        #pragma unroll
        for (int j = 0; j < 4; ++j)
            #pragma unroll
            for (int r = 0; r < 4; ++r) acc[i][j][r] = 0.0f;

    #pragma unroll
    for (int i = 0; i < 8; ++i) {
        int idx = t + i * 256;
        int r = idx >> 4, c = idx & 15;
        int gr = row0 + r; if (gr > N_NODES - 1) gr = N_NODES - 1;
        ushort4 w0 = *(const ushort4*)(A + (size_t)gr * F_HID + c * 8);
        ushort4 w1 = *(const ushort4*)(A + (size_t)gr * F_HID + c * 8 + 4);
        *(ushort4*)(&As[r][c * 8]) = w0;
        *(ushort4*)(&As[r][c * 8 + 4]) = w1;
    }
    #pragma unroll
    for (int i = 0; i < 4; ++i) {
        int idx = t + i * 256;
        int n = idx >> 4, c = idx & 15;
        ushort4 w0 = *(const ushort4*)(Wt + (size_t)n * F_HID + c * 8);
        ushort4 w1 = *(const ushort4*)(Wt + (size_t)n * F_HID + c * 8 + 4);
        *(ushort4*)(&Ws[n][c * 8]) = w0;
        *(ushort4*)(&Ws[n][c * 8 + 4]) = w1;
    }
    __syncthreads();
    #pragma unroll
    for (int ks = 0; ks < 4; ++ks) {
        int k0 = ks * 32;
        short8 af[2];
        #pragma unroll
        for (int rt = 0; rt < 2; ++rt)
            af[rt] = *(const short8*)(&As[wave * 32 + rt * 16 + l16][k0 + quad * 8]);
        #pragma unroll
        for (int ct = 0; ct < 4; ++ct) {
            short8 bf = *(const short8*)(&Ws[ct * 16 + l16][k0 + quad * 8]);
            acc[0][ct] = __builtin_amdgcn_mfma_f32_16x16x32_bf16(af[0], bf, acc[0][ct], 0, 0, 0);
            acc[1][ct] = __builtin_amdgcn_mfma_f32_16x16x32_bf16(af[1], bf, acc[1][ct], 0, 0, 0);
        }
    }
    #pragma unroll
    for (int rt = 0; rt < 2; ++rt) {
        #pragma unroll
        for (int ct = 0; ct < 4; ++ct) {
            #pragma unroll
            for (int r = 0; r < 4; ++r) {
                int row = row0 + wave * 32 + rt * 16 + quad * 4 + r;
                if (row < N_NODES)
                    C[(size_t)row * F_OUT_P + ct * 16 + l16] = f2bf(acc[rt][ct][r]);
            }
        }
    }
}

// ---------------- agg2 + bias + log_softmax (wave per node, unroll x4) ----------------
__global__ __launch_bounds__(256) void k_agg2(const unsigned short* __restrict__ h2,
                                              const int* __restrict__ off,
                                              const int2* __restrict__ edges,
                                              const float* __restrict__ dinv,
                                              const float* __restrict__ b2,
                                              float* __restrict__ out) {
    int node = blockIdx.x * 4 + (threadIdx.x >> 6);
    int lane = threadIdx.x & 63;
    if (node >= N_NODES) return;
    int s0 = off[node], s1 = off[node + 1];
    float dn = dinv[node];
    float acc = dn * bf2f(h2[(size_t)node * F_OUT_P + lane]);
    int e = s0;
    for (; e + 4 <= s1; e += 4) {
        int2 e0 = edges[e], e1 = edges[e + 1], e2 = edges[e + 2], e3 = edges[e + 3];
        float v0 = bf2f(h2[(size_t)e0.x * F_OUT_P + lane]);
        float v1 = bf2f(h2[(size_t)e1.x * F_OUT_P + lane]);
        float v2 = bf2f(h2[(size_t)e2.x * F_OUT_P + lane]);
        float v3 = bf2f(h2[(size_t)e3.x * F_OUT_P + lane]);
        acc += __int_as_float(e0.y) * v0 + __int_as_float(e1.y) * v1
             + __int_as_float(e2.y) * v2 + __int_as_float(e3.y) * v3;
    }
    for (; e < s1; ++e) {
        int2 e0 = edges[e];
        acc += __int_as_float(e0.y) * bf2f(h2[(size_t)e0.x * F_OUT_P + lane]);
    }
    float v = (lane < F_OUT) ? (acc * dn + b2[lane]) : -3.4e38f;
    float m = v;
    #pragma unroll
    for (int o = 32; o > 0; o >>= 1) m = fmaxf(m, __shfl_xor(m, o));
    float ex = (lane < F_OUT) ? __expf(v - m) : 0.0f;
    float s = ex;
    #pragma unroll
    for (int o = 32; o > 0; o >>= 1) s += __shfl_xor(s, o);
    float ls = __logf(s);
    if (lane < F_OUT) out[(size_t)node * F_OUT + lane] = v - m - ls;
}

// ---------------- launch ----------------
static inline char* alignup(char* p) {
    return (char*)(((uintptr_t)p + 255) & ~(uintptr_t)255);
}

extern "C" void kernel_launch(void* const* d_in, const int* in_sizes, int n_in,
                              void* d_out, int out_size, void* d_ws, size_t ws_size,
                              hipStream_t stream) {
    const float* x  = (const float*)d_in[0];
    const int*   ei = (const int*)d_in[1];
    const float* W1 = (const float*)d_in[2];
    const float* b1 = (const float*)d_in[3];
    const float* W2 = (const float*)d_in[4];
    const float* b2 = (const float*)d_in[5];
    float* out = (float*)d_out;

    char* w = (char*)d_ws;
    int* gtot  = (int*)w;             w = alignup(w + (size_t)NBKT * 4);
    int* boff  = (int*)w;             w = alignup(w + (size_t)(NBKT + 1) * 4);
    int* bcur  = (int*)w;             w = alignup(w + (size_t)NBKT * 4);
    int* off   = (int*)w;             w = alignup(w + (size_t)(N_NODES + 1) * 4);
    float* dinv = (float*)w;          w = alignup(w + (size_t)N_NODES * 4);
    int2* edges = (int2*)w;           w = alignup(w + (size_t)N_EDGES * 8);
    unsigned short* W1t = (unsigned short*)w;  w = alignup(w + (size_t)F_HID * F_IN * 2);
    unsigned short* W2t = (unsigned short*)w;  w = alignup(w + (size_t)F_OUT_P * F_HID * 2);
    unsigned short* h   = (unsigned short*)w;  w = alignup(w + (size_t)N_NODES * F_HID * 2);
    unsigned short* h1  = (unsigned short*)w;  w = alignup(w + (size_t)N_NODES * F_HID * 2);
    unsigned short* h2  = (unsigned short*)w;  w = alignup(w + (size_t)N_NODES * F_OUT_P * 2);
    // lifetime-disjoint aliases (binned dead before gemm1 writes h; ssrc dead before agg1 writes h1)
    unsigned int* binned = (unsigned int*)h;   // 6.4 MB < 25.6 MB
    int* ssrc            = (int*)h1;           // 6.4 MB < 25.6 MB

    const int* srcp = ei;
    const int* dstp = ei + N_EDGES;

    hipMemsetAsync(gtot, 0, (size_t)NBKT * 4, stream);
    k_hist<<<P1_NBLK, 256, 0, stream>>>(dstp, gtot);
    k_bktscan<<<1, 256, 0, stream>>>(gtot, boff, bcur);
    k_bin<<<P1_NBLK, 256, 0, stream>>>(srcp, dstp, bcur, binned);
    k_place<<<NBKT, 256, 0, stream>>>(binned, boff, off, dinv, ssrc);
    k_mkrec<<<(N_EDGES / 4 + 255) / 256, 256, 0, stream>>>(ssrc, dinv, edges);

    k_convW1<<<(F_IN * F_HID + 255) / 256, 256, 0, stream>>>(W1, W1t);
    k_convW2<<<(F_OUT_P * F_HID + 255) / 256, 256, 0, stream>>>(W2, W2t);

    k_gemm1<<<(N_NODES + 127) / 128, 256, 0, stream>>>(x, W1t, h);
    k_agg1<<<(N_NODES + 7) / 8, 256, 0, stream>>>(h, off, edges, dinv, b1, h1);
    k_gemm2<<<(N_NODES + 127) / 128, 256, 0, stream>>>(h1, W2t, h2);
    k_agg2<<<(N_NODES + 3) / 4, 256, 0, stream>>>(h2, off, edges, dinv, b2, out);
}

// Round 5
// 398.398 us; speedup vs baseline: 2.2360x; 1.0108x over previous
//
#include <hip/hip_runtime.h>
#include <cstdint>
#include <cstddef>

#define N_NODES 100000
#define N_EDGES 1600000
#define F_IN 256
#define F_HID 128
#define F_OUT 40
#define F_OUT_P 64   // h2 padded cols (bf16)

#define BKT_SHIFT 8
#define BKT_SIZE 256
#define NBKT ((N_NODES + BKT_SIZE - 1) / BKT_SIZE)   // 391
#define P1_EPT 16
#define P1_EPB (256 * P1_EPT)                        // 4096 edges/block
#define P1_NBLK ((N_EDGES + P1_EPB - 1) / P1_EPB)    // 391

typedef __attribute__((ext_vector_type(8))) short short8;
typedef __attribute__((ext_vector_type(4))) float floatx4;

__device__ __forceinline__ float bf2f(unsigned short u) {
    return __uint_as_float(((unsigned int)u) << 16);
}
__device__ __forceinline__ unsigned short f2bf(float f) {
    unsigned int x = __float_as_uint(f);
    x += 0x7fffu + ((x >> 16) & 1u);   // RNE
    return (unsigned short)(x >> 16);
}

// ---------------- P1a: bucket histogram ----------------
__global__ __launch_bounds__(256) void k_hist(const int* __restrict__ dst,
                                              int* __restrict__ gtot) {
    __shared__ int hist[NBKT];
    for (int i = threadIdx.x; i < NBKT; i += 256) hist[i] = 0;
    __syncthreads();
    int base = blockIdx.x * P1_EPB;
    #pragma unroll
    for (int i = 0; i < P1_EPT; ++i) {
        int e = base + threadIdx.x + i * 256;
        if (e < N_EDGES) atomicAdd(&hist[dst[e] >> BKT_SHIFT], 1);
    }
    __syncthreads();
    for (int i = threadIdx.x; i < NBKT; i += 256)
        if (hist[i]) atomicAdd(&gtot[i], hist[i]);
}

// ---------------- P1b: scan bucket totals ----------------
__global__ __launch_bounds__(256) void k_bktscan(const int* __restrict__ gtot,
                                                 int* __restrict__ boff,
                                                 int* __restrict__ bcur) {
    __shared__ int lds[NBKT + 1];
    int t = threadIdx.x;
    for (int i = t; i < NBKT; i += 256) lds[i] = gtot[i];
    __syncthreads();
    if (t == 0) {
        int run = 0;
        for (int i = 0; i < NBKT; ++i) { int v = lds[i]; lds[i] = run; run += v; }
        lds[NBKT] = run;
    }
    __syncthreads();
    for (int i = t; i <= NBKT; i += 256) {
        boff[i] = lds[i];
        if (i < NBKT) bcur[i] = lds[i];
    }
}

// ---------------- P1c: bin edges by bucket (4B packed records) ----------------
__global__ __launch_bounds__(256) void k_bin(const int* __restrict__ src,
                                             const int* __restrict__ dst,
                                             int* __restrict__ bcur,
                                             unsigned int* __restrict__ binned) {
    __shared__ int hist[NBKT];
    __shared__ int baseg[NBKT];
    __shared__ int cnt2[NBKT];
    for (int i = threadIdx.x; i < NBKT; i += 256) { hist[i] = 0; cnt2[i] = 0; }
    __syncthreads();
    int base = blockIdx.x * P1_EPB;
    int s[P1_EPT], d[P1_EPT];
    #pragma unroll
    for (int i = 0; i < P1_EPT; ++i) {
        int e = base + threadIdx.x + i * 256;
        if (e < N_EDGES) {
            s[i] = src[e]; d[i] = dst[e];
            atomicAdd(&hist[d[i] >> BKT_SHIFT], 1);
        } else d[i] = -1;
    }
    __syncthreads();
    for (int i = threadIdx.x; i < NBKT; i += 256)
        baseg[i] = hist[i] ? atomicAdd(&bcur[i], hist[i]) : 0;
    __syncthreads();
    #pragma unroll
    for (int i = 0; i < P1_EPT; ++i) {
        if (d[i] >= 0) {
            int b = d[i] >> BKT_SHIFT;
            int r = atomicAdd(&cnt2[b], 1);
            binned[baseg[b] + r] =
                (unsigned int)s[i] | ((unsigned int)(d[i] & (BKT_SIZE - 1)) << 17);
        }
    }
}

// ---------------- P2: per-bucket place -> CSR, off[], dinv[] (no global atomics) ----------------
__global__ __launch_bounds__(256) void k_place(const unsigned int* __restrict__ binned,
                                               const int* __restrict__ boff,
                                               int* __restrict__ off,
                                               float* __restrict__ dinv,
                                               int* __restrict__ ssrc) {
    __shared__ int cnt[BKT_SIZE];
    __shared__ int ioff[BKT_SIZE];
    __shared__ int sexcl[BKT_SIZE];
    int b = blockIdx.x, t = threadIdx.x;
    int e0 = boff[b], e1 = boff[b + 1];
    cnt[t] = 0;
    __syncthreads();
    for (int i = e0 + t; i < e1; i += 256)
        atomicAdd(&cnt[binned[i] >> 17], 1);
    __syncthreads();
    int v = cnt[t];
    ioff[t] = v;
    __syncthreads();
    for (int ofs = 1; ofs < 256; ofs <<= 1) {
        int y = (t >= ofs) ? ioff[t - ofs] : 0;
        __syncthreads();
        ioff[t] += y;
        __syncthreads();
    }
    int excl = ioff[t] - v;   // exclusive prefix within bucket
    int n = b * BKT_SIZE + t;
    if (n < N_NODES) {
        off[n] = e0 + excl;
        dinv[n] = rsqrtf((float)v + 1.0f);
    }
    if (b == NBKT - 1 && t == 0) off[N_NODES] = N_EDGES;
    __syncthreads();
    cnt[t] = 0;
    sexcl[t] = excl;
    __syncthreads();
    for (int i = e0 + t; i < e1; i += 256) {
        unsigned int rec = binned[i];
        int dl = rec >> 17;
        int r = atomicAdd(&cnt[dl], 1);
        ssrc[e0 + sexcl[dl] + r] = (int)(rec & 0x1FFFFu);
    }
}

// ---------------- P3: build (src, dinv[src]) records ----------------
__global__ __launch_bounds__(256) void k_mkrec(const int* __restrict__ ssrc,
                                               const float* __restrict__ dinv,
                                               int2* __restrict__ edges) {
    int i = blockIdx.x * blockDim.x + threadIdx.x;   // groups of 4
    if (i < N_EDGES / 4) {
        int4 s4 = ((const int4*)ssrc)[i];
        int4* ep = (int4*)(edges + (size_t)i * 4);
        ep[0] = make_int4(s4.x, __float_as_int(dinv[s4.x]),
                          s4.y, __float_as_int(dinv[s4.y]));
        ep[1] = make_int4(s4.z, __float_as_int(dinv[s4.z]),
                          s4.w, __float_as_int(dinv[s4.w]));
    }
}

// ---------------- weight conversion (merged) ----------------
__global__ void k_convW(const float* __restrict__ W1, const float* __restrict__ W2,
                        unsigned short* __restrict__ W1t, unsigned short* __restrict__ W2t) {
    int i = blockIdx.x * blockDim.x + threadIdx.x;
    if (i < F_IN * F_HID) {
        int k = i >> 7, n = i & 127;
        W1t[n * F_IN + k] = f2bf(W1[i]);
    } else {
        int j = i - F_IN * F_HID;
        if (j < F_OUT_P * F_HID) {
            int k = j >> 6, n = j & 63;
            float v = (n < F_OUT) ? W2[k * F_OUT + n] : 0.0f;
            W2t[n * F_HID + k] = f2bf(v);
        }
    }
}

// ---------------- GEMM1 (MFMA bf16): x[N,256]f32 @ W1 -> h[N,128]bf16 ----------------
__global__ __launch_bounds__(256) void k_gemm1(const float* __restrict__ A,
                                               const unsigned short* __restrict__ Wt,
                                               unsigned short* __restrict__ C) {
    __shared__ unsigned short As[128][40];
    __shared__ unsigned short Ws[128][40];
    int t = threadIdx.x;
    int wave = t >> 6, lane = t & 63;
    int quad = lane >> 4, l16 = lane & 15;
    int row0 = blockIdx.x * 128;
    floatx4 acc[2][8];
    #pragma unroll
    for (int i = 0; i < 2; ++i)
        #pragma unroll
        for (int j = 0; j < 8; ++j)
            #pragma unroll
            for (int r = 0; r < 4; ++r) acc[i][j][r] = 0.0f;

    for (int k0 = 0; k0 < F_IN; k0 += 32) {
        #pragma unroll
        for (int i = 0; i < 4; ++i) {
            int idx = t + i * 256;
            int r = idx >> 3, c = idx & 7;
            int gr = row0 + r; if (gr > N_NODES - 1) gr = N_NODES - 1;
            float4 va = *(const float4*)(A + (size_t)gr * F_IN + k0 + c * 4);
            ushort4 u;
            u.x = f2bf(va.x); u.y = f2bf(va.y); u.z = f2bf(va.z); u.w = f2bf(va.w);
            *(ushort4*)(&As[r][c * 4]) = u;
        }
        #pragma unroll
        for (int i = 0; i < 2; ++i) {
            int idx = t + i * 256;
            int n = idx >> 2, c = idx & 3;
            ushort4 w0 = *(const ushort4*)(Wt + (size_t)n * F_IN + k0 + c * 8);
            ushort4 w1 = *(const ushort4*)(Wt + (size_t)n * F_IN + k0 + c * 8 + 4);
            *(ushort4*)(&Ws[n][c * 8]) = w0;
            *(ushort4*)(&Ws[n][c * 8 + 4]) = w1;
        }
        __syncthreads();
        short8 af[2];
        #pragma unroll
        for (int rt = 0; rt < 2; ++rt)
            af[rt] = *(const short8*)(&As[wave * 32 + rt * 16 + l16][quad * 8]);
        #pragma unroll
        for (int ct = 0; ct < 8; ++ct) {
            short8 bf = *(const short8*)(&Ws[ct * 16 + l16][quad * 8]);
            acc[0][ct] = __builtin_amdgcn_mfma_f32_16x16x32_bf16(af[0], bf, acc[0][ct], 0, 0, 0);
            acc[1][ct] = __builtin_amdgcn_mfma_f32_16x16x32_bf16(af[1], bf, acc[1][ct], 0, 0, 0);
        }
        __syncthreads();
    }
    #pragma unroll
    for (int rt = 0; rt < 2; ++rt) {
        #pragma unroll
        for (int ct = 0; ct < 8; ++ct) {
            #pragma unroll
            for (int r = 0; r < 4; ++r) {
                int row = row0 + wave * 32 + rt * 16 + quad * 4 + r;
                if (row < N_NODES)
                    C[(size_t)row * F_HID + ct * 16 + l16] = f2bf(acc[rt][ct][r]);
            }
        }
    }
}

// ---------------- agg1: one node per wave, halves process even/odd edges ----------------
// lanes 0-31: even edges, lanes 32-63: odd edges; ushort4 (4 cols) per lane.
// unroll x4 per half -> 8 gathers of 256B in flight per wave.
__global__ __launch_bounds__(256) void k_agg1(const unsigned short* __restrict__ h_,
                                              const int* __restrict__ off,
                                              const int2* __restrict__ edges,
                                              const float* __restrict__ dinv,
                                              const float* __restrict__ b1,
                                              unsigned short* __restrict__ h1_) {
    const ushort4* h = (const ushort4*)h_;   // row = 32 ushort4
    ushort4* h1 = (ushort4*)h1_;
    int node = blockIdx.x * 4 + (threadIdx.x >> 6);
    int lane = threadIdx.x & 63;
    int half = lane >> 5, l32 = lane & 31;
    if (node >= N_NODES) return;
    int s0 = off[node], s1 = off[node + 1];
    int nE = s1 - s0;
    float dn = dinv[node];
    float ax = 0.f, ay = 0.f, az = 0.f, aw = 0.f;
    if (half == 0) {
        ushort4 sv = h[(size_t)node * 32 + l32];
        ax = dn * bf2f(sv.x); ay = dn * bf2f(sv.y);
        az = dn * bf2f(sv.z); aw = dn * bf2f(sv.w);
    }
    int end2 = s0 + (nE & ~1);   // paired region (even count)
    int e = s0 + half;
    for (; e + 6 < end2; e += 8) {
        int2 r0 = edges[e], r1 = edges[e + 2], r2 = edges[e + 4], r3 = edges[e + 6];
        ushort4 v0 = h[(size_t)r0.x * 32 + l32];
        ushort4 v1 = h[(size_t)r1.x * 32 + l32];
        ushort4 v2 = h[(size_t)r2.x * 32 + l32];
        ushort4 v3 = h[(size_t)r3.x * 32 + l32];
        float w0 = __int_as_float(r0.y), w1 = __int_as_float(r1.y);
        float w2 = __int_as_float(r2.y), w3 = __int_as_float(r3.y);
        ax += w0 * bf2f(v0.x) + w1 * bf2f(v1.x) + w2 * bf2f(v2.x) + w3 * bf2f(v3.x);
        ay += w0 * bf2f(v0.y) + w1 * bf2f(v1.y) + w2 * bf2f(v2.y) + w3 * bf2f(v3.y);
        az += w0 * bf2f(v0.z) + w1 * bf2f(v1.z) + w2 * bf2f(v2.z) + w3 * bf2f(v3.z);
        aw += w0 * bf2f(v0.w) + w1 * bf2f(v1.w) + w2 * bf2f(v2.w) + w3 * bf2f(v3.w);
    }
    for (; e < end2; e += 2) {
        int2 r0 = edges[e];
        ushort4 v0 = h[(size_t)r0.x * 32 + l32];
        float w0 = __int_as_float(r0.y);
        ax += w0 * bf2f(v0.x); ay += w0 * bf2f(v0.y);
        az += w0 * bf2f(v0.z); aw += w0 * bf2f(v0.w);
    }
    if ((nE & 1) && half == 0) {
        int2 r0 = edges[s1 - 1];
        ushort4 v0 = h[(size_t)r0.x * 32 + l32];
        float w0 = __int_as_float(r0.y);
        ax += w0 * bf2f(v0.x); ay += w0 * bf2f(v0.y);
        az += w0 * bf2f(v0.z); aw += w0 * bf2f(v0.w);
    }
    ax += __shfl_xor(ax, 32); ay += __shfl_xor(ay, 32);
    az += __shfl_xor(az, 32); aw += __shfl_xor(aw, 32);
    if (half == 0) {
        float4 bb = ((const float4*)b1)[l32];
        ushort4 r;
        r.x = f2bf(fmaxf(ax * dn + bb.x, 0.0f));
        r.y = f2bf(fmaxf(ay * dn + bb.y, 0.0f));
        r.z = f2bf(fmaxf(az * dn + bb.z, 0.0f));
        r.w = f2bf(fmaxf(aw * dn + bb.w, 0.0f));
        h1[(size_t)node * 32 + l32] = r;
    }
}

// ---------------- GEMM2 (MFMA bf16): h1[N,128]bf16 @ W2 -> h2[N,64]bf16 ----------------
__global__ __launch_bounds__(256) void k_gemm2(const unsigned short* __restrict__ A,
                                               const unsigned short* __restrict__ Wt,
                                               unsigned short* __restrict__ C) {
    __shared__ unsigned short As[128][136];
    __shared__ unsigned short Ws[64][136];
    int t = threadIdx.x;
    int wave = t >> 6, lane = t & 63;
    int quad = lane >> 4, l16 = lane & 15;
    int row0 = blockIdx.x * 128;
    floatx4 acc[2][4];
    #pragma unroll
    for (int i = 0; i < 2; ++i)
        #pragma unroll
        for (int j = 0; j < 4; ++j)
            #pragma unroll
            for (int r = 0; r < 4; ++r) acc[i][j][r] = 0.0f;

    #pragma unroll
    for (int i = 0; i < 8; ++i) {
        int idx = t + i * 256;
        int r = idx >> 4, c = idx & 15;
        int gr = row0 + r; if (gr > N_NODES - 1) gr = N_NODES - 1;
        ushort4 w0 = *(const ushort4*)(A + (size_t)gr * F_HID + c * 8);
        ushort4 w1 = *(const ushort4*)(A + (size_t)gr * F_HID + c * 8 + 4);
        *(ushort4*)(&As[r][c * 8]) = w0;
        *(ushort4*)(&As[r][c * 8 + 4]) = w1;
    }
    #pragma unroll
    for (int i = 0; i < 4; ++i) {
        int idx = t + i * 256;
        int n = idx >> 4, c = idx & 15;
        ushort4 w0 = *(const ushort4*)(Wt + (size_t)n * F_HID + c * 8);
        ushort4 w1 = *(const ushort4*)(Wt + (size_t)n * F_HID + c * 8 + 4);
        *(ushort4*)(&Ws[n][c * 8]) = w0;
        *(ushort4*)(&Ws[n][c * 8 + 4]) = w1;
    }
    __syncthreads();
    #pragma unroll
    for (int ks = 0; ks < 4; ++ks) {
        int k0 = ks * 32;
        short8 af[2];
        #pragma unroll
        for (int rt = 0; rt < 2; ++rt)
            af[rt] = *(const short8*)(&As[wave * 32 + rt * 16 + l16][k0 + quad * 8]);
        #pragma unroll
        for (int ct = 0; ct < 4; ++ct) {
            short8 bf = *(const short8*)(&Ws[ct * 16 + l16][k0 + quad * 8]);
            acc[0][ct] = __builtin_amdgcn_mfma_f32_16x16x32_bf16(af[0], bf, acc[0][ct], 0, 0, 0);
            acc[1][ct] = __builtin_amdgcn_mfma_f32_16x16x32_bf16(af[1], bf, acc[1][ct], 0, 0, 0);
        }
    }
    #pragma unroll
    for (int rt = 0; rt < 2; ++rt) {
        #pragma unroll
        for (int ct = 0; ct < 4; ++ct) {
            #pragma unroll
            for (int r = 0; r < 4; ++r) {
                int row = row0 + wave * 32 + rt * 16 + quad * 4 + r;
                if (row < N_NODES)
                    C[(size_t)row * F_OUT_P + ct * 16 + l16] = f2bf(acc[rt][ct][r]);
            }
        }
    }
}

// ---------------- agg2 + bias + log_softmax: one node per wave ----------------
// lanes 0-31 even edges, 32-63 odd edges; each lane = 2 cols (packed uint of 2 bf16).
__global__ __launch_bounds__(256) void k_agg2(const unsigned short* __restrict__ h2_,
                                              const int* __restrict__ off,
                                              const int2* __restrict__ edges,
                                              const float* __restrict__ dinv,
                                              const float* __restrict__ b2,
                                              float* __restrict__ out) {
    const unsigned int* h2 = (const unsigned int*)h2_;  // row = 32 uints (64 cols)
    int node = blockIdx.x * 4 + (threadIdx.x >> 6);
    int lane = threadIdx.x & 63;
    int half = lane >> 5, l32 = lane & 31;
    if (node >= N_NODES) return;
    int s0 = off[node], s1 = off[node + 1];
    int nE = s1 - s0;
    float dn = dinv[node];
    float a0 = 0.f, a1 = 0.f;
    if (half == 0) {
        unsigned int u = h2[(size_t)node * 32 + l32];
        a0 = dn * __uint_as_float(u << 16);
        a1 = dn * __uint_as_float(u & 0xFFFF0000u);
    }
    int end2 = s0 + (nE & ~1);
    int e = s0 + half;
    for (; e + 6 < end2; e += 8) {
        int2 r0 = edges[e], r1 = edges[e + 2], r2 = edges[e + 4], r3 = edges[e + 6];
        unsigned int u0 = h2[(size_t)r0.x * 32 + l32];
        unsigned int u1 = h2[(size_t)r1.x * 32 + l32];
        unsigned int u2 = h2[(size_t)r2.x * 32 + l32];
        unsigned int u3 = h2[(size_t)r3.x * 32 + l32];
        float w0 = __int_as_float(r0.y), w1 = __int_as_float(r1.y);
        float w2 = __int_as_float(r2.y), w3 = __int_as_float(r3.y);
        a0 += w0 * __uint_as_float(u0 << 16) + w1 * __uint_as_float(u1 << 16)
            + w2 * __uint_as_float(u2 << 16) + w3 * __uint_as_float(u3 << 16);
        a1 += w0 * __uint_as_float(u0 & 0xFFFF0000u) + w1 * __uint_as_float(u1 & 0xFFFF0000u)
            + w2 * __uint_as_float(u2 & 0xFFFF0000u) + w3 * __uint_as_float(u3 & 0xFFFF0000u);
    }
    for (; e < end2; e += 2) {
        int2 r0 = edges[e];
        unsigned int u0 = h2[(size_t)r0.x * 32 + l32];
        float w0 = __int_as_float(r0.y);
        a0 += w0 * __uint_as_float(u0 << 16);
        a1 += w0 * __uint_as_float(u0 & 0xFFFF0000u);
    }
    if ((nE & 1) && half == 0) {
        int2 r0 = edges[s1 - 1];
        unsigned int u0 = h2[(size_t)r0.x * 32 + l32];
        float w0 = __int_as_float(r0.y);
        a0 += w0 * __uint_as_float(u0 << 16);
        a1 += w0 * __uint_as_float(u0 & 0xFFFF0000u);
    }
    a0 += __shfl_xor(a0, 32);
    a1 += __shfl_xor(a1, 32);
    // all lanes now hold identical sums for cols {2*l32, 2*l32+1}
    int c0 = l32 * 2;
    float v0 = (c0 < F_OUT)     ? (a0 * dn + b2[c0])     : -3.4e38f;
    float v1 = (c0 + 1 < F_OUT) ? (a1 * dn + b2[c0 + 1]) : -3.4e38f;
    float m = fmaxf(v0, v1);
    #pragma unroll
    for (int o = 16; o > 0; o >>= 1) m = fmaxf(m, __shfl_xor(m, o));
    float ex = ((c0 < F_OUT) ? __expf(v0 - m) : 0.0f)
             + ((c0 + 1 < F_OUT) ? __expf(v1 - m) : 0.0f);
    #pragma unroll
    for (int o = 16; o > 0; o >>= 1) ex += __shfl_xor(ex, o);
    float ls = __logf(ex);
    if (half == 0 && c0 < F_OUT) {
        float2 o2 = make_float2(v0 - m - ls, v1 - m - ls);
        *(float2*)(out + (size_t)node * F_OUT + c0) = o2;
    }
}

// ---------------- launch ----------------
static inline char* alignup(char* p) {
    return (char*)(((uintptr_t)p + 255) & ~(uintptr_t)255);
}

extern "C" void kernel_launch(void* const* d_in, const int* in_sizes, int n_in,
                              void* d_out, int out_size, void* d_ws, size_t ws_size,
                              hipStream_t stream) {
    const float* x  = (const float*)d_in[0];
    const int*   ei = (const int*)d_in[1];
    const float* W1 = (const float*)d_in[2];
    const float* b1 = (const float*)d_in[3];
    const float* W2 = (const float*)d_in[4];
    const float* b2 = (const float*)d_in[5];
    float* out = (float*)d_out;

    char* w = (char*)d_ws;
    int* gtot  = (int*)w;             w = alignup(w + (size_t)NBKT * 4);
    int* boff  = (int*)w;             w = alignup(w + (size_t)(NBKT + 1) * 4);
    int* bcur  = (int*)w;             w = alignup(w + (size_t)NBKT * 4);
    int* off   = (int*)w;             w = alignup(w + (size_t)(N_NODES + 1) * 4);
    float* dinv = (float*)w;          w = alignup(w + (size_t)N_NODES * 4);
    int2* edges = (int2*)w;           w = alignup(w + (size_t)N_EDGES * 8);
    unsigned short* W1t = (unsigned short*)w;  w = alignup(w + (size_t)F_HID * F_IN * 2);
    unsigned short* W2t = (unsigned short*)w;  w = alignup(w + (size_t)F_OUT_P * F_HID * 2);
    unsigned short* h   = (unsigned short*)w;  w = alignup(w + (size_t)N_NODES * F_HID * 2);
    unsigned short* h1  = (unsigned short*)w;  w = alignup(w + (size_t)N_NODES * F_HID * 2);
    unsigned short* h2  = (unsigned short*)w;  w = alignup(w + (size_t)N_NODES * F_OUT_P * 2);
    // lifetime-disjoint aliases (binned dead before gemm1 writes h; ssrc dead before agg1 writes h1)
    unsigned int* binned = (unsigned int*)h;   // 6.4 MB < 25.6 MB
    int* ssrc            = (int*)h1;           // 6.4 MB < 25.6 MB

    const int* srcp = ei;
    const int* dstp = ei + N_EDGES;

    hipMemsetAsync(gtot, 0, (size_t)NBKT * 4, stream);
    k_hist<<<P1_NBLK, 256, 0, stream>>>(dstp, gtot);
    k_bktscan<<<1, 256, 0, stream>>>(gtot, boff, bcur);
    k_bin<<<P1_NBLK, 256, 0, stream>>>(srcp, dstp, bcur, binned);
    k_place<<<NBKT, 256, 0, stream>>>(binned, boff, off, dinv, ssrc);
    k_mkrec<<<(N_EDGES / 4 + 255) / 256, 256, 0, stream>>>(ssrc, dinv, edges);

    k_convW<<<(F_IN * F_HID + F_OUT_P * F_HID + 255) / 256, 256, 0, stream>>>(W1, W2, W1t, W2t);

    k_gemm1<<<(N_NODES + 127) / 128, 256, 0, stream>>>(x, W1t, h);
    k_agg1<<<(N_NODES + 3) / 4, 256, 0, stream>>>(h, off, edges, dinv, b1, h1);
    k_gemm2<<<(N_NODES + 127) / 128, 256, 0, stream>>>(h1, W2t, h2);
    k_agg2<<<(N_NODES + 3) / 4, 256, 0, stream>>>(h2, off, edges, dinv, b2, out);
}

// Round 6
// 395.925 us; speedup vs baseline: 2.2500x; 1.0062x over previous
//
#include <hip/hip_runtime.h>
#include <cstdint>
#include <cstddef>

#define N_NODES 100000
#define N_EDGES 1600000
#define F_IN 256
#define F_HID 128
#define F_OUT 40
#define F_OUT_P 64   // h2 padded cols (bf16)

#define BKT_SHIFT 8
#define BKT_SIZE 256
#define NBKT ((N_NODES + BKT_SIZE - 1) / BKT_SIZE)   // 391
#define P1_EPT 16
#define P1_EPB (256 * P1_EPT)                        // 4096 edges/block
#define P1_NBLK ((N_EDGES + P1_EPB - 1) / P1_EPB)    // 391

typedef __attribute__((ext_vector_type(8))) short short8;
typedef __attribute__((ext_vector_type(4))) float floatx4;

__device__ __forceinline__ float bf2f(unsigned short u) {
    return __uint_as_float(((unsigned int)u) << 16);
}
__device__ __forceinline__ unsigned short f2bf(float f) {
    unsigned int x = __float_as_uint(f);
    x += 0x7fffu + ((x >> 16) & 1u);   // RNE
    return (unsigned short)(x >> 16);
}
__device__ __forceinline__ float lo16(unsigned int u) { return __uint_as_float(u << 16); }
__device__ __forceinline__ float hi16(unsigned int u) { return __uint_as_float(u & 0xFFFF0000u); }

// ---------------- P1a: bucket histogram ----------------
__global__ __launch_bounds__(256) void k_hist(const int* __restrict__ dst,
                                              int* __restrict__ gtot) {
    __shared__ int hist[NBKT];
    for (int i = threadIdx.x; i < NBKT; i += 256) hist[i] = 0;
    __syncthreads();
    int base = blockIdx.x * P1_EPB;
    #pragma unroll
    for (int i = 0; i < P1_EPT; ++i) {
        int e = base + threadIdx.x + i * 256;
        if (e < N_EDGES) atomicAdd(&hist[dst[e] >> BKT_SHIFT], 1);
    }
    __syncthreads();
    for (int i = threadIdx.x; i < NBKT; i += 256)
        if (hist[i]) atomicAdd(&gtot[i], hist[i]);
}

// ---------------- P1b: scan bucket totals ----------------
__global__ __launch_bounds__(256) void k_bktscan(const int* __restrict__ gtot,
                                                 int* __restrict__ boff,
                                                 int* __restrict__ bcur) {
    __shared__ int lds[NBKT + 1];
    int t = threadIdx.x;
    for (int i = t; i < NBKT; i += 256) lds[i] = gtot[i];
    __syncthreads();
    if (t == 0) {
        int run = 0;
        for (int i = 0; i < NBKT; ++i) { int v = lds[i]; lds[i] = run; run += v; }
        lds[NBKT] = run;
    }
    __syncthreads();
    for (int i = t; i <= NBKT; i += 256) {
        boff[i] = lds[i];
        if (i < NBKT) bcur[i] = lds[i];
    }
}

// ---------------- P1c: bin edges by bucket (4B packed records) ----------------
__global__ __launch_bounds__(256) void k_bin(const int* __restrict__ src,
                                             const int* __restrict__ dst,
                                             int* __restrict__ bcur,
                                             unsigned int* __restrict__ binned) {
    __shared__ int hist[NBKT];
    __shared__ int baseg[NBKT];
    __shared__ int cnt2[NBKT];
    for (int i = threadIdx.x; i < NBKT; i += 256) { hist[i] = 0; cnt2[i] = 0; }
    __syncthreads();
    int base = blockIdx.x * P1_EPB;
    int s[P1_EPT], d[P1_EPT];
    #pragma unroll
    for (int i = 0; i < P1_EPT; ++i) {
        int e = base + threadIdx.x + i * 256;
        if (e < N_EDGES) {
            s[i] = src[e]; d[i] = dst[e];
            atomicAdd(&hist[d[i] >> BKT_SHIFT], 1);
        } else d[i] = -1;
    }
    __syncthreads();
    for (int i = threadIdx.x; i < NBKT; i += 256)
        baseg[i] = hist[i] ? atomicAdd(&bcur[i], hist[i]) : 0;
    __syncthreads();
    #pragma unroll
    for (int i = 0; i < P1_EPT; ++i) {
        if (d[i] >= 0) {
            int b = d[i] >> BKT_SHIFT;
            int r = atomicAdd(&cnt2[b], 1);
            binned[baseg[b] + r] =
                (unsigned int)s[i] | ((unsigned int)(d[i] & (BKT_SIZE - 1)) << 17);
        }
    }
}

// ---------------- P2: per-bucket place -> CSR, off[], dinv[] (no global atomics) ----------------
__global__ __launch_bounds__(256) void k_place(const unsigned int* __restrict__ binned,
                                               const int* __restrict__ boff,
                                               int* __restrict__ off,
                                               float* __restrict__ dinv,
                                               int* __restrict__ ssrc) {
    __shared__ int cnt[BKT_SIZE];
    __shared__ int ioff[BKT_SIZE];
    __shared__ int sexcl[BKT_SIZE];
    int b = blockIdx.x, t = threadIdx.x;
    int e0 = boff[b], e1 = boff[b + 1];
    cnt[t] = 0;
    __syncthreads();
    for (int i = e0 + t; i < e1; i += 256)
        atomicAdd(&cnt[binned[i] >> 17], 1);
    __syncthreads();
    int v = cnt[t];
    ioff[t] = v;
    __syncthreads();
    for (int ofs = 1; ofs < 256; ofs <<= 1) {
        int y = (t >= ofs) ? ioff[t - ofs] : 0;
        __syncthreads();
        ioff[t] += y;
        __syncthreads();
    }
    int excl = ioff[t] - v;   // exclusive prefix within bucket
    int n = b * BKT_SIZE + t;
    if (n < N_NODES) {
        off[n] = e0 + excl;
        dinv[n] = rsqrtf((float)v + 1.0f);
    }
    if (b == NBKT - 1 && t == 0) off[N_NODES] = N_EDGES;
    __syncthreads();
    cnt[t] = 0;
    sexcl[t] = excl;
    __syncthreads();
    for (int i = e0 + t; i < e1; i += 256) {
        unsigned int rec = binned[i];
        int dl = rec >> 17;
        int r = atomicAdd(&cnt[dl], 1);
        ssrc[e0 + sexcl[dl] + r] = (int)(rec & 0x1FFFFu);
    }
}

// ---------------- P3: build (src, dinv[src]) records ----------------
__global__ __launch_bounds__(256) void k_mkrec(const int* __restrict__ ssrc,
                                               const float* __restrict__ dinv,
                                               int2* __restrict__ edges) {
    int i = blockIdx.x * blockDim.x + threadIdx.x;   // groups of 4
    if (i < N_EDGES / 4) {
        int4 s4 = ((const int4*)ssrc)[i];
        int4* ep = (int4*)(edges + (size_t)i * 4);
        ep[0] = make_int4(s4.x, __float_as_int(dinv[s4.x]),
                          s4.y, __float_as_int(dinv[s4.y]));
        ep[1] = make_int4(s4.z, __float_as_int(dinv[s4.z]),
                          s4.w, __float_as_int(dinv[s4.w]));
    }
}

// ---------------- weight conversion (merged) ----------------
__global__ void k_convW(const float* __restrict__ W1, const float* __restrict__ W2,
                        unsigned short* __restrict__ W1t, unsigned short* __restrict__ W2t) {
    int i = blockIdx.x * blockDim.x + threadIdx.x;
    if (i < F_IN * F_HID) {
        int k = i >> 7, n = i & 127;
        W1t[n * F_IN + k] = f2bf(W1[i]);
    } else {
        int j = i - F_IN * F_HID;
        if (j < F_OUT_P * F_HID) {
            int k = j >> 6, n = j & 63;
            float v = (n < F_OUT) ? W2[k * F_OUT + n] : 0.0f;
            W2t[n * F_HID + k] = f2bf(v);
        }
    }
}

// ---------------- GEMM1 (MFMA bf16): x[N,256]f32 @ W1 -> h[N,128]bf16 ----------------
__global__ __launch_bounds__(256) void k_gemm1(const float* __restrict__ A,
                                               const unsigned short* __restrict__ Wt,
                                               unsigned short* __restrict__ C) {
    __shared__ unsigned short As[128][40];
    __shared__ unsigned short Ws[128][40];
    int t = threadIdx.x;
    int wave = t >> 6, lane = t & 63;
    int quad = lane >> 4, l16 = lane & 15;
    int row0 = blockIdx.x * 128;
    floatx4 acc[2][8];
    #pragma unroll
    for (int i = 0; i < 2; ++i)
        #pragma unroll
        for (int j = 0; j < 8; ++j)
            #pragma unroll
            for (int r = 0; r < 4; ++r) acc[i][j][r] = 0.0f;

    for (int k0 = 0; k0 < F_IN; k0 += 32) {
        #pragma unroll
        for (int i = 0; i < 4; ++i) {
            int idx = t + i * 256;
            int r = idx >> 3, c = idx & 7;
            int gr = row0 + r; if (gr > N_NODES - 1) gr = N_NODES - 1;
            float4 va = *(const float4*)(A + (size_t)gr * F_IN + k0 + c * 4);
            ushort4 u;
            u.x = f2bf(va.x); u.y = f2bf(va.y); u.z = f2bf(va.z); u.w = f2bf(va.w);
            *(ushort4*)(&As[r][c * 4]) = u;
        }
        #pragma unroll
        for (int i = 0; i < 2; ++i) {
            int idx = t + i * 256;
            int n = idx >> 2, c = idx & 3;
            ushort4 w0 = *(const ushort4*)(Wt + (size_t)n * F_IN + k0 + c * 8);
            ushort4 w1 = *(const ushort4*)(Wt + (size_t)n * F_IN + k0 + c * 8 + 4);
            *(ushort4*)(&Ws[n][c * 8]) = w0;
            *(ushort4*)(&Ws[n][c * 8 + 4]) = w1;
        }
        __syncthreads();
        short8 af[2];
        #pragma unroll
        for (int rt = 0; rt < 2; ++rt)
            af[rt] = *(const short8*)(&As[wave * 32 + rt * 16 + l16][quad * 8]);
        #pragma unroll
        for (int ct = 0; ct < 8; ++ct) {
            short8 bf = *(const short8*)(&Ws[ct * 16 + l16][quad * 8]);
            acc[0][ct] = __builtin_amdgcn_mfma_f32_16x16x32_bf16(af[0], bf, acc[0][ct], 0, 0, 0);
            acc[1][ct] = __builtin_amdgcn_mfma_f32_16x16x32_bf16(af[1], bf, acc[1][ct], 0, 0, 0);
        }
        __syncthreads();
    }
    #pragma unroll
    for (int rt = 0; rt < 2; ++rt) {
        #pragma unroll
        for (int ct = 0; ct < 8; ++ct) {
            #pragma unroll
            for (int r = 0; r < 4; ++r) {
                int row = row0 + wave * 32 + rt * 16 + quad * 4 + r;
                if (row < N_NODES)
                    C[(size_t)row * F_HID + ct * 16 + l16] = f2bf(acc[rt][ct][r]);
            }
        }
    }
}

// ---------------- agg1: one node per wave, 4 quarter-waves x 4 edges in flight ----------------
// lane quarter q handles edges e = s0+q, +4, +8, ... ; each lane loads uint4 (8 cols).
// unroll x4 -> 16 gathers of 256B in flight per wave.
#define ACC8(u4, wgt) { \
    a[0] += wgt * lo16(u4.x); a[1] += wgt * hi16(u4.x); \
    a[2] += wgt * lo16(u4.y); a[3] += wgt * hi16(u4.y); \
    a[4] += wgt * lo16(u4.z); a[5] += wgt * hi16(u4.z); \
    a[6] += wgt * lo16(u4.w); a[7] += wgt * hi16(u4.w); }

__global__ __launch_bounds__(256) void k_agg1(const unsigned short* __restrict__ h_,
                                              const int* __restrict__ off,
                                              const int2* __restrict__ edges,
                                              const float* __restrict__ dinv,
                                              const float* __restrict__ b1,
                                              unsigned short* __restrict__ h1_) {
    const uint4* h = (const uint4*)h_;   // row = 16 uint4 (128 bf16)
    uint4* h1 = (uint4*)h1_;
    int node = blockIdx.x * 4 + (threadIdx.x >> 6);
    int lane = threadIdx.x & 63;
    int q = lane >> 4, l16 = lane & 15;
    if (node >= N_NODES) return;
    int s0 = off[node], s1 = off[node + 1];
    int nE = s1 - s0;
    float dn = dinv[node];
    float a[8] = {};
    if (q == 0) {
        uint4 sv = h[(size_t)node * 16 + l16];
        ACC8(sv, dn);
    }
    int end4 = s0 + (nE & ~3);
    int e = s0 + q;
    for (; e + 12 < end4; e += 16) {
        int2 r0 = edges[e], r1 = edges[e + 4], r2 = edges[e + 8], r3 = edges[e + 12];
        uint4 v0 = h[(size_t)r0.x * 16 + l16];
        uint4 v1 = h[(size_t)r1.x * 16 + l16];
        uint4 v2 = h[(size_t)r2.x * 16 + l16];
        uint4 v3 = h[(size_t)r3.x * 16 + l16];
        ACC8(v0, __int_as_float(r0.y));
        ACC8(v1, __int_as_float(r1.y));
        ACC8(v2, __int_as_float(r2.y));
        ACC8(v3, __int_as_float(r3.y));
    }
    for (; e < end4; e += 4) {
        int2 r0 = edges[e];
        uint4 v0 = h[(size_t)r0.x * 16 + l16];
        ACC8(v0, __int_as_float(r0.y));
    }
    if (q < (nE & 3)) {
        int2 r0 = edges[end4 + q];
        uint4 v0 = h[(size_t)r0.x * 16 + l16];
        ACC8(v0, __int_as_float(r0.y));
    }
    #pragma unroll
    for (int i = 0; i < 8; ++i) {
        a[i] += __shfl_xor(a[i], 16);
        a[i] += __shfl_xor(a[i], 32);
    }
    if (q == 0) {
        float4 bb0 = ((const float4*)b1)[l16 * 2];
        float4 bb1 = ((const float4*)b1)[l16 * 2 + 1];
        unsigned short c0 = f2bf(fmaxf(a[0] * dn + bb0.x, 0.0f));
        unsigned short c1 = f2bf(fmaxf(a[1] * dn + bb0.y, 0.0f));
        unsigned short c2 = f2bf(fmaxf(a[2] * dn + bb0.z, 0.0f));
        unsigned short c3 = f2bf(fmaxf(a[3] * dn + bb0.w, 0.0f));
        unsigned short c4 = f2bf(fmaxf(a[4] * dn + bb1.x, 0.0f));
        unsigned short c5 = f2bf(fmaxf(a[5] * dn + bb1.y, 0.0f));
        unsigned short c6 = f2bf(fmaxf(a[6] * dn + bb1.z, 0.0f));
        unsigned short c7 = f2bf(fmaxf(a[7] * dn + bb1.w, 0.0f));
        uint4 r;
        r.x = (unsigned int)c0 | ((unsigned int)c1 << 16);
        r.y = (unsigned int)c2 | ((unsigned int)c3 << 16);
        r.z = (unsigned int)c4 | ((unsigned int)c5 << 16);
        r.w = (unsigned int)c6 | ((unsigned int)c7 << 16);
        h1[(size_t)node * 16 + l16] = r;
    }
}

// ---------------- GEMM2 (MFMA bf16): h1[N,128]bf16 @ W2 -> h2[N,64]bf16 ----------------
__global__ __launch_bounds__(256) void k_gemm2(const unsigned short* __restrict__ A,
                                               const unsigned short* __restrict__ Wt,
                                               unsigned short* __restrict__ C) {
    __shared__ unsigned short As[128][136];
    __shared__ unsigned short Ws[64][136];
    int t = threadIdx.x;
    int wave = t >> 6, lane = t & 63;
    int quad = lane >> 4, l16 = lane & 15;
    int row0 = blockIdx.x * 128;
    floatx4 acc[2][4];
    #pragma unroll
    for (int i = 0; i < 2; ++i)
        #pragma unroll
        for (int j = 0; j < 4; ++j)
            #pragma unroll
            for (int r = 0; r < 4; ++r) acc[i][j][r] = 0.0f;

    #pragma unroll
    for (int i = 0; i < 8; ++i) {
        int idx = t + i * 256;
        int r = idx >> 4, c = idx & 15;
        int gr = row0 + r; if (gr > N_NODES - 1) gr = N_NODES - 1;
        ushort4 w0 = *(const ushort4*)(A + (size_t)gr * F_HID + c * 8);
        ushort4 w1 = *(const ushort4*)(A + (size_t)gr * F_HID + c * 8 + 4);
        *(ushort4*)(&As[r][c * 8]) = w0;
        *(ushort4*)(&As[r][c * 8 + 4]) = w1;
    }
    #pragma unroll
    for (int i = 0; i < 4; ++i) {
        int idx = t + i * 256;
        int n = idx >> 4, c = idx & 15;
        ushort4 w0 = *(const ushort4*)(Wt + (size_t)n * F_HID + c * 8);
        ushort4 w1 = *(const ushort4*)(Wt + (size_t)n * F_HID + c * 8 + 4);
        *(ushort4*)(&Ws[n][c * 8]) = w0;
        *(ushort4*)(&Ws[n][c * 8 + 4]) = w1;
    }
    __syncthreads();
    #pragma unroll
    for (int ks = 0; ks < 4; ++ks) {
        int k0 = ks * 32;
        short8 af[2];
        #pragma unroll
        for (int rt = 0; rt < 2; ++rt)
            af[rt] = *(const short8*)(&As[wave * 32 + rt * 16 + l16][k0 + quad * 8]);
        #pragma unroll
        for (int ct = 0; ct < 4; ++ct) {
            short8 bf = *(const short8*)(&Ws[ct * 16 + l16][k0 + quad * 8]);
            acc[0][ct] = __builtin_amdgcn_mfma_f32_16x16x32_bf16(af[0], bf, acc[0][ct], 0, 0, 0);
            acc[1][ct] = __builtin_amdgcn_mfma_f32_16x16x32_bf16(af[1], bf, acc[1][ct], 0, 0, 0);
        }
    }
    #pragma unroll
    for (int rt = 0; rt < 2; ++rt) {
        #pragma unroll
        for (int ct = 0; ct < 4; ++ct) {
            #pragma unroll
            for (int r = 0; r < 4; ++r) {
                int row = row0 + wave * 32 + rt * 16 + quad * 4 + r;
                if (row < N_NODES)
                    C[(size_t)row * F_OUT_P + ct * 16 + l16] = f2bf(acc[rt][ct][r]);
            }
        }
    }
}

// ---------------- agg2 + bias + log_softmax: 4 quarter-waves x 4 edges in flight ----------------
// lane quarter q handles edges e = s0+q, +4, ... ; each lane loads uint2 (4 cols).
#define ACC4(u2, wgt) { \
    a[0] += wgt * lo16(u2.x); a[1] += wgt * hi16(u2.x); \
    a[2] += wgt * lo16(u2.y); a[3] += wgt * hi16(u2.y); }

__global__ __launch_bounds__(256) void k_agg2(const unsigned short* __restrict__ h2_,
                                              const int* __restrict__ off,
                                              const int2* __restrict__ edges,
                                              const float* __restrict__ dinv,
                                              const float* __restrict__ b2,
                                              float* __restrict__ out) {
    const uint2* h2 = (const uint2*)h2_;  // row = 16 uint2 (64 bf16)
    int node = blockIdx.x * 4 + (threadIdx.x >> 6);
    int lane = threadIdx.x & 63;
    int q = lane >> 4, l16 = lane & 15;
    if (node >= N_NODES) return;
    int s0 = off[node], s1 = off[node + 1];
    int nE = s1 - s0;
    float dn = dinv[node];
    float a[4] = {};
    if (q == 0) {
        uint2 sv = h2[(size_t)node * 16 + l16];
        ACC4(sv, dn);
    }
    int end4 = s0 + (nE & ~3);
    int e = s0 + q;
    for (; e + 12 < end4; e += 16) {
        int2 r0 = edges[e], r1 = edges[e + 4], r2 = edges[e + 8], r3 = edges[e + 12];
        uint2 v0 = h2[(size_t)r0.x * 16 + l16];
        uint2 v1 = h2[(size_t)r1.x * 16 + l16];
        uint2 v2 = h2[(size_t)r2.x * 16 + l16];
        uint2 v3 = h2[(size_t)r3.x * 16 + l16];
        ACC4(v0, __int_as_float(r0.y));
        ACC4(v1, __int_as_float(r1.y));
        ACC4(v2, __int_as_float(r2.y));
        ACC4(v3, __int_as_float(r3.y));
    }
    for (; e < end4; e += 4) {
        int2 r0 = edges[e];
        uint2 v0 = h2[(size_t)r0.x * 16 + l16];
        ACC4(v0, __int_as_float(r0.y));
    }
    if (q < (nE & 3)) {
        int2 r0 = edges[end4 + q];
        uint2 v0 = h2[(size_t)r0.x * 16 + l16];
        ACC4(v0, __int_as_float(r0.y));
    }
    #pragma unroll
    for (int i = 0; i < 4; ++i) {
        a[i] += __shfl_xor(a[i], 16);
        a[i] += __shfl_xor(a[i], 32);
    }
    // all lanes hold sums for cols 4*l16 .. 4*l16+3
    int c0 = l16 * 4;
    float v0 = (c0 < F_OUT)     ? (a[0] * dn + b2[c0])     : -3.4e38f;
    float v1 = (c0 + 1 < F_OUT) ? (a[1] * dn + b2[c0 + 1]) : -3.4e38f;
    float v2 = (c0 + 2 < F_OUT) ? (a[2] * dn + b2[c0 + 2]) : -3.4e38f;
    float v3 = (c0 + 3 < F_OUT) ? (a[3] * dn + b2[c0 + 3]) : -3.4e38f;
    float m = fmaxf(fmaxf(v0, v1), fmaxf(v2, v3));
    #pragma unroll
    for (int o = 8; o > 0; o >>= 1) m = fmaxf(m, __shfl_xor(m, o));
    float ex = ((c0 < F_OUT)     ? __expf(v0 - m) : 0.0f)
             + ((c0 + 1 < F_OUT) ? __expf(v1 - m) : 0.0f)
             + ((c0 + 2 < F_OUT) ? __expf(v2 - m) : 0.0f)
             + ((c0 + 3 < F_OUT) ? __expf(v3 - m) : 0.0f);
    #pragma unroll
    for (int o = 8; o > 0; o >>= 1) ex += __shfl_xor(ex, o);
    float ls = __logf(ex);
    if (q == 0 && c0 < F_OUT) {
        float4 o4 = make_float4(v0 - m - ls, v1 - m - ls, v2 - m - ls, v3 - m - ls);
        *(float4*)(out + (size_t)node * F_OUT + c0) = o4;
    }
}

// ---------------- launch ----------------
static inline char* alignup(char* p) {
    return (char*)(((uintptr_t)p + 255) & ~(uintptr_t)255);
}

extern "C" void kernel_launch(void* const* d_in, const int* in_sizes, int n_in,
                              void* d_out, int out_size, void* d_ws, size_t ws_size,
                              hipStream_t stream) {
    const float* x  = (const float*)d_in[0];
    const int*   ei = (const int*)d_in[1];
    const float* W1 = (const float*)d_in[2];
    const float* b1 = (const float*)d_in[3];
    const float* W2 = (const float*)d_in[4];
    const float* b2 = (const float*)d_in[5];
    float* out = (float*)d_out;

    char* w = (char*)d_ws;
    int* gtot  = (int*)w;             w = alignup(w + (size_t)NBKT * 4);
    int* boff  = (int*)w;             w = alignup(w + (size_t)(NBKT + 1) * 4);
    int* bcur  = (int*)w;             w = alignup(w + (size_t)NBKT * 4);
    int* off   = (int*)w;             w = alignup(w + (size_t)(N_NODES + 1) * 4);
    float* dinv = (float*)w;          w = alignup(w + (size_t)N_NODES * 4);
    int2* edges = (int2*)w;           w = alignup(w + (size_t)N_EDGES * 8);
    unsigned short* W1t = (unsigned short*)w;  w = alignup(w + (size_t)F_HID * F_IN * 2);
    unsigned short* W2t = (unsigned short*)w;  w = alignup(w + (size_t)F_OUT_P * F_HID * 2);
    unsigned short* h   = (unsigned short*)w;  w = alignup(w + (size_t)N_NODES * F_HID * 2);
    unsigned short* h1  = (unsigned short*)w;  w = alignup(w + (size_t)N_NODES * F_HID * 2);
    unsigned short* h2  = (unsigned short*)w;  w = alignup(w + (size_t)N_NODES * F_OUT_P * 2);
    // lifetime-disjoint aliases (binned dead before gemm1 writes h; ssrc dead before agg1 writes h1)
    unsigned int* binned = (unsigned int*)h;   // 6.4 MB < 25.6 MB
    int* ssrc            = (int*)h1;           // 6.4 MB < 25.6 MB

    const int* srcp = ei;
    const int* dstp = ei + N_EDGES;

    hipMemsetAsync(gtot, 0, (size_t)NBKT * 4, stream);
    k_hist<<<P1_NBLK, 256, 0, stream>>>(dstp, gtot);
    k_bktscan<<<1, 256, 0, stream>>>(gtot, boff, bcur);
    k_bin<<<P1_NBLK, 256, 0, stream>>>(srcp, dstp, bcur, binned);
    k_place<<<NBKT, 256, 0, stream>>>(binned, boff, off, dinv, ssrc);
    k_mkrec<<<(N_EDGES / 4 + 255) / 256, 256, 0, stream>>>(ssrc, dinv, edges);

    k_convW<<<(F_IN * F_HID + F_OUT_P * F_HID + 255) / 256, 256, 0, stream>>>(W1, W2, W1t, W2t);

    k_gemm1<<<(N_NODES + 127) / 128, 256, 0, stream>>>(x, W1t, h);
    k_agg1<<<(N_NODES + 3) / 4, 256, 0, stream>>>(h, off, edges, dinv, b1, h1);
    k_gemm2<<<(N_NODES + 127) / 128, 256, 0, stream>>>(h1, W2t, h2);
    k_agg2<<<(N_NODES + 3) / 4, 256, 0, stream>>>(h2, off, edges, dinv, b2, out);
}